// Round 8
// baseline (1896.558 us; speedup 1.0000x reference)
//
#include <hip/hip_runtime.h>
#include <cstdint>
#include <cstddef>

// NCA: x = bilinear(seed)->1024x1024 NHWC **f16 state**; 64x [conv3x3(8->32)+gelu,
// conv1x1(32->8)*0.1, masked add]; project 8->1. Convs via mfma_f32_16x16x32_f16,
// operand-swapped:
//   conv3x3: mfma(A=W1frag, B=pixelfrag) -> D[ch(regs)][pixel(lane&15)]
//   conv1x1: mfma(A=h(direct from gelu, k''-order), B=W2frag) -> D[pixel(regs)][outch(lane)]
// f16 state: staging is a raw 16B copy (no cvt); update reads center pixel from the LDS
// tile (no global re-read) and writes f16 — per-step global traffic = 16MB in + 16MB out.
// dx staged in wave-local f16 LDS (intra-wave ds ordering, no 2nd barrier). ONE barrier.
// Update math in f32: x' = RTN_f16(x + dx*(0.1*mask)).
// PRNG: jax threefry2x32 partitionable: subkey[i]=raw pair tf2x32((0,42),(0,i));
// bits[p]=o0^o1 of tf2x32(subkey,(0,p)); mask = (bits>>9) > 2^22.

#define HH 1024
#define WW 1024
#define SD 8
#define HID 32
#define TX 32
#define TY 16

typedef _Float16 f16x8 __attribute__((ext_vector_type(8)));
typedef float f32x4 __attribute__((ext_vector_type(4)));
typedef uint32_t u32x4 __attribute__((ext_vector_type(4)));

__host__ __device__ inline uint32_t rotl32(uint32_t x, int n) {
  return (x << n) | (x >> (32 - n));
}

__host__ __device__ inline void tf2x32(uint32_t k0, uint32_t k1,
                                       uint32_t x0, uint32_t x1,
                                       uint32_t& o0, uint32_t& o1) {
  uint32_t ks0 = k0, ks1 = k1, ks2 = k0 ^ k1 ^ 0x1BD11BDAu;
  x0 += ks0; x1 += ks1;
#define TFR(r) { x0 += x1; x1 = rotl32(x1, (r)); x1 ^= x0; }
  TFR(13) TFR(15) TFR(26) TFR(6)  x0 += ks1; x1 += ks2 + 1u;
  TFR(17) TFR(29) TFR(16) TFR(24) x0 += ks2; x1 += ks0 + 2u;
  TFR(13) TFR(15) TFR(26) TFR(6)  x0 += ks0; x1 += ks1 + 3u;
  TFR(17) TFR(29) TFR(16) TFR(24) x0 += ks1; x1 += ks2 + 4u;
  TFR(13) TFR(15) TFR(26) TFR(6)  x0 += ks2; x1 += ks0 + 5u;
#undef TFR
  o0 = x0; o1 = x1;
}

// gelu(x) = 0.5x + 0.5|x|*erf(|x|/sqrt2); erf via A&S 7.1.26 branchless, |err|<=1.5e-7.
__device__ inline float gelu_fast(float x) {
  const float ax = __builtin_fabsf(x);
  const float ay = 0.70710678118654752f * ax;
  const float t = __builtin_amdgcn_rcpf(fmaf(0.3275911f, ay, 1.0f));
  float p = fmaf(1.061405429f, t, -1.453152027f);
  p = fmaf(p, t, 1.421413741f);
  p = fmaf(p, t, -0.284496736f);
  p = fmaf(p, t, 0.254829592f);
  p *= t;
  const float e = __expf(-ay * ay);
  const float erfv = fmaf(-p, e, 1.0f);
  return fmaf(0.5f * ax, erfv, 0.5f * x);
}

// ---- bilinear upsample 8x8 -> 1024x1024, NHWC f16 out (RTN per element) ----
__global__ void init_kernel(const float* __restrict__ seed, _Float16* __restrict__ dst) {
  int p = blockIdx.x * blockDim.x + threadIdx.x;
  if (p >= HH * WW) return;
  int y = p >> 10, x = p & 1023;
  float fy = (y + 0.5f) * (8.0f / HH) - 0.5f;
  float fx = (x + 0.5f) * (8.0f / WW) - 0.5f;
  int y0 = (int)floorf(fy); float wy = fy - (float)y0;
  int x0 = (int)floorf(fx); float wx = fx - (float)x0;
  int y0c = min(max(y0, 0), 7), y1c = min(max(y0 + 1, 0), 7);
  int x0c = min(max(x0, 0), 7), x1c = min(max(x0 + 1, 0), 7);
  f16x8 v;
#pragma unroll
  for (int c = 0; c < SD; ++c) {
    const float* s = seed + c * 64;
    float v00 = s[y0c * 8 + x0c], v01 = s[y0c * 8 + x1c];
    float v10 = s[y1c * 8 + x0c], v11 = s[y1c * 8 + x1c];
    float v0 = v00 + (v01 - v00) * wx;
    float v1 = v10 + (v11 - v10) * wx;
    v[c] = (_Float16)(v0 + (v1 - v0) * wy);
  }
  *(f16x8*)(dst + (size_t)p * 8) = v;
}

// ---- pack W1 (A-operand frags) and W2 (B-operand, k''-order) ----
// W1f: row n = nt*16+(lane&15) [out-ch], k = kc*32+(lane>>4)*8+j, k=tap*8+c -> tap=kc*4+q, c=j
// W2f: row n = lane&15 [out-ch, <8 valid], k'' = (lane>>4)*8+jj,
//      channel(k'') = (lane>>4)*4 + (jj&3) + ((jj>>2)<<4)
__global__ void prep_kernel(const float* __restrict__ W1, const float* __restrict__ W2,
                            _Float16* __restrict__ w1f, _Float16* __restrict__ w2f) {
  int tid = threadIdx.x;
  for (int i = tid; i < 2 * 3 * 64; i += 256) {
    int nt = i / 192, rem = i % 192;
    int kc = rem / 64, lane = rem % 64;
    int n = nt * 16 + (lane & 15);
    int tap = kc * 4 + (lane >> 4);
#pragma unroll
    for (int j = 0; j < 8; ++j) {
      float v = (tap < 9) ? W1[(n * SD + j) * 9 + tap] : 0.0f;
      w1f[i * 8 + j] = (_Float16)v;
    }
  }
  if (tid < 64) {
    int n = tid & 15, qk = tid >> 4;
#pragma unroll
    for (int jj = 0; jj < 8; ++jj) {
      int ch = qk * 4 + (jj & 3) + ((jj >> 2) << 4);
      float v = (n < 8) ? W2[n * HID + ch] : 0.0f;
      w2f[tid * 8 + jj] = (_Float16)v;
    }
  }
}

// ---- fused NCA step: one barrier; f16 state; update from LDS tile ----
__global__ __launch_bounds__(256, 8) void step_kernel(
    const _Float16* __restrict__ src, _Float16* __restrict__ dst,
    const _Float16* __restrict__ w1f, const _Float16* __restrict__ w2f,
    const float* __restrict__ b1, const float* __restrict__ b2,
    uint32_t key0, uint32_t key1) {
  __shared__ _Float16 tile[(TY + 2) * (TX + 2) * SD];   // NHWC f16, halo +1 (9792 B)
  __shared__ _Float16 dxw[4][128 * 8];                  // per-wave dx f16, [px][ch] (8 KB)

  const int tid = threadIdx.x;
  const int bx = blockIdx.x, by = blockIdx.y;
  const int lane = tid & 63, w = tid >> 6;
  const int m = lane & 15, q = lane >> 4;

  // ---- weight fragments + biases (global, L1-hot) ----
  f16x8 af[2][3];
#pragma unroll
  for (int nt = 0; nt < 2; ++nt)
#pragma unroll
    for (int kc = 0; kc < 3; ++kc)
      af[nt][kc] = *(const f16x8*)(w1f + ((nt * 3 + kc) * 64 + lane) * 8);
  const f16x8 w2fr = *(const f16x8*)(w2f + lane * 8);
  const f32x4 b1q0 = *(const f32x4*)(b1 + q * 4);        // ch q*4+r
  const f32x4 b1q1 = *(const f32x4*)(b1 + 16 + q * 4);   // ch 16+q*4+r
  const float b2v = b2[m & 7];

  // ---- stage f16 NHWC -> LDS tile, raw 16B copy (zero pad outside) ----
  for (int i = tid; i < (TY + 2) * (TX + 2); i += 256) {
    int ly = i / (TX + 2), lx = i % (TX + 2);
    int gy = by * TY + ly - 1, gx = bx * TX + lx - 1;
    u32x4 v = {0u, 0u, 0u, 0u};
    if ((unsigned)gy < HH && (unsigned)gx < WW)
      v = *(const u32x4*)(src + (size_t)(gy * WW + gx) * 8);
    *(u32x4*)&tile[i * 8] = v;
  }

  // ---- threefry masks for this thread's 2 update pixels (wave-local mapping) ----
  float maskf[2];
#pragma unroll
  for (int half = 0; half < 2; ++half) {
    const int p = w * 128 + half * 64 + lane;
    const uint32_t gp = (uint32_t)((by * TY + (p >> 5)) * WW + bx * TX + (p & 31));
    uint32_t r0, r1;
    tf2x32(key0, key1, 0u, gp, r0, r1);
    maskf[half] = (((r0 ^ r1) >> 9) > 0x400000u) ? 0.1f : 0.0f;  // 0.1*mask folded
  }
  __syncthreads();

  // per-lane B1 (pixel) base pointers for the 3 K-chunks (taps 9..11: zero A-rows, clamp addr)
  const _Float16* bp_[3];
#pragma unroll
  for (int kc = 0; kc < 3; ++kc) {
    int t = kc * 4 + q; if (t > 8) t = 0;
    bp_[kc] = &tile[((t / 3) * (TX + 2) + m + (t % 3)) * 8];
  }

#pragma unroll
  for (int r4 = 0; r4 < 4; ++r4) {
    const int y = w * 4 + r4;                       // local row 0..15, wave-uniform
#pragma unroll
    for (int xh = 0; xh < 2; ++xh) {
      const int x0 = xh * 16;
      f32x4 acc0 = b1q0, acc1 = b1q1;               // bias folded into C
#pragma unroll
      for (int kc = 0; kc < 3; ++kc) {
        const f16x8 bfrag = *(const f16x8*)(bp_[kc] + (y * (TX + 2) + x0) * 8);
        acc0 = __builtin_amdgcn_mfma_f32_16x16x32_f16(af[0][kc], bfrag, acc0, 0, 0, 0);
        acc1 = __builtin_amdgcn_mfma_f32_16x16x32_f16(af[1][kc], bfrag, acc1, 0, 0, 0);
      }
      // lane holds hidden ch {q*4+r} (acc0) and {16+q*4+r} (acc1) of pixel x0+m.
      u32x4 a2d;
      {
        float g0 = gelu_fast(acc0[0]), g1 = gelu_fast(acc0[1]);
        float g2 = gelu_fast(acc0[2]), g3 = gelu_fast(acc0[3]);
        float g4 = gelu_fast(acc1[0]), g5 = gelu_fast(acc1[1]);
        float g6 = gelu_fast(acc1[2]), g7 = gelu_fast(acc1[3]);
        a2d[0] = __builtin_bit_cast(uint32_t, __builtin_amdgcn_cvt_pkrtz(g0, g1));
        a2d[1] = __builtin_bit_cast(uint32_t, __builtin_amdgcn_cvt_pkrtz(g2, g3));
        a2d[2] = __builtin_bit_cast(uint32_t, __builtin_amdgcn_cvt_pkrtz(g4, g5));
        a2d[3] = __builtin_bit_cast(uint32_t, __builtin_amdgcn_cvt_pkrtz(g6, g7));
      }
      const f16x8 a2 = __builtin_bit_cast(f16x8, a2d);
      f32x4 acc2 = {b2v, b2v, b2v, b2v};
      acc2 = __builtin_amdgcn_mfma_f32_16x16x32_f16(a2, w2fr, acc2, 0, 0, 0);
      // D2: lane&15 = out-ch (m<8 valid), regs = pixels x0+q*4+r -> wave-local f16 LDS stage
      if (m < 8) {
        _Float16* wp = &dxw[w][(r4 * 32 + x0 + q * 4) * 8 + m];
        wp[0]  = (_Float16)acc2[0];
        wp[8]  = (_Float16)acc2[1];
        wp[16] = (_Float16)acc2[2];
        wp[24] = (_Float16)acc2[3];
      }
    }
  }

  // ---- wave-local coalesced update: x' = RTN_f16(x + dx*(0.1*mask)), x from LDS tile ----
  // (intra-wave ds_write->ds_read ordering; no second barrier)
#pragma unroll
  for (int half = 0; half < 2; ++half) {
    const int pw = half * 64 + lane;                // pixel within wave region, 0..127
    const int p = w * 128 + pw;
    const int py = p >> 5, px = p & 31;
    const uint32_t gp = (uint32_t)((by * TY + py) * WW + bx * TX + px);
    const float mk = maskf[half];
    const f16x8 xi = *(const f16x8*)&tile[((py + 1) * (TX + 2) + px + 1) * 8];
    const f16x8 dx = *(const f16x8*)&dxw[w][pw * 8];
    f16x8 xo;
#pragma unroll
    for (int j = 0; j < 8; ++j)
      xo[j] = (_Float16)fmaf((float)dx[j], mk, (float)xi[j]);
    *(f16x8*)(dst + (size_t)gp * 8) = xo;
  }
}

// ---- projection: out[p] = bp + sum_c x[p][c]*Wp[c] (NHWC f16 state, f32 math/out) ----
__global__ void proj_kernel(const _Float16* __restrict__ x,
                            const float* __restrict__ Wp,
                            const float* __restrict__ bp,
                            float* __restrict__ out) {
  int p = blockIdx.x * blockDim.x + threadIdx.x;
  if (p >= HH * WW) return;
  const f16x8 xv = *(const f16x8*)(x + (size_t)p * 8);
  float acc = bp[0];
#pragma unroll
  for (int c = 0; c < SD; ++c) acc = fmaf((float)xv[c], Wp[c], acc);
  out[p] = acc;
}

extern "C" void kernel_launch(void* const* d_in, const int* in_sizes, int n_in,
                              void* d_out, int out_size, void* d_ws, size_t ws_size,
                              hipStream_t stream) {
  (void)in_sizes; (void)n_in; (void)out_size; (void)ws_size;
  const float* seed = (const float*)d_in[0];
  const float* W1   = (const float*)d_in[1];
  const float* b1   = (const float*)d_in[2];
  const float* W2   = (const float*)d_in[3];
  const float* b2   = (const float*)d_in[4];
  const float* Wp   = (const float*)d_in[5];
  const float* bp   = (const float*)d_in[6];
  float* out  = (float*)d_out;
  _Float16* buf0 = (_Float16*)d_ws;
  _Float16* buf1 = buf0 + (size_t)SD * HH * WW;
  _Float16* w1f  = buf1 + (size_t)SD * HH * WW;
  _Float16* w2f  = w1f + 2 * 3 * 64 * 8;

  // 64 subkeys of jax.random.split(jax.random.key(42), 64) (raw pairs, no xor)
  uint32_t ka[64], kb[64];
  for (int i = 0; i < 64; ++i) tf2x32(0u, 42u, 0u, (uint32_t)i, ka[i], kb[i]);

  hipLaunchKernelGGL(prep_kernel, dim3(1), dim3(256), 0, stream, W1, W2, w1f, w2f);
  hipLaunchKernelGGL(init_kernel, dim3((HH * WW) / 256), dim3(256), 0, stream, seed, buf0);

  dim3 grid(WW / TX, HH / TY);
  _Float16* s = buf0; _Float16* d = buf1;
  for (int i = 0; i < 64; ++i) {
    hipLaunchKernelGGL(step_kernel, grid, dim3(256), 0, stream,
                       s, d, w1f, w2f, b1, b2, ka[i], kb[i]);
    _Float16* t = s; s = d; d = t;
  }
  hipLaunchKernelGGL(proj_kernel, dim3((HH * WW) / 256), dim3(256), 0, stream,
                     s, Wp, bp, out);
}

// Round 9
// 1731.540 us; speedup vs baseline: 1.0953x; 1.0953x over previous
//
#include <hip/hip_runtime.h>
#include <cstdint>
#include <cstddef>

// NCA, 2 steps fused per launch. State: NHWC f16, double-buffered in d_ws.
// Per block (output 16x32): stage 20x36 halo-2 tile (tileA) -> step A conv over the
// 18x34 ring-extended domain (ring values recomputed bit-identically by neighbors; no
// seams) -> assemble x_{i+1} into tileB (zeroing out-of-image ring = SAME padding) ->
// step B conv over 16x32 -> masked update -> dst. 3 barriers / 2 steps.
// Convs: mfma_f32_16x16x32_f16 operand-swapped (A=weights, B=pixels):
//   conv3x3 D: row(q*4+reg)=hidden-ch, col(lane&15)=pixel; K-order k=tap*8+c.
//   gelu'd accs pack directly into conv1x1 A-operand (k''-order W2, no LDS transpose).
//   conv1x1 D: row=pixel-in-group, col=out-ch -> wave-local dxw scatter.
// gelu: exact erf via A&S 7.1.26 branchless (|err|<=1.5e-7).
// PRNG: jax threefry2x32 partitionable: subkey[i]=raw pair tf2x32((0,42),(0,i));
// bits[p]=o0^o1 of tf2x32(subkey,(0,p)); mask = (bits>>9) > 2^22.

#define HH 1024
#define WW 1024
#define SD 8
#define TX 32
#define TY 16
#define NA 612           // step-A domain: 18*34
#define SWA 36           // tileA row stride (pixels)
#define SWB 34           // tileB row stride (pixels)

typedef _Float16 f16x8 __attribute__((ext_vector_type(8)));
typedef float f32x4 __attribute__((ext_vector_type(4)));
typedef uint32_t u32x4 __attribute__((ext_vector_type(4)));

__host__ __device__ inline uint32_t rotl32(uint32_t x, int n) {
  return (x << n) | (x >> (32 - n));
}

__host__ __device__ inline void tf2x32(uint32_t k0, uint32_t k1,
                                       uint32_t x0, uint32_t x1,
                                       uint32_t& o0, uint32_t& o1) {
  uint32_t ks0 = k0, ks1 = k1, ks2 = k0 ^ k1 ^ 0x1BD11BDAu;
  x0 += ks0; x1 += ks1;
#define TFR(r) { x0 += x1; x1 = rotl32(x1, (r)); x1 ^= x0; }
  TFR(13) TFR(15) TFR(26) TFR(6)  x0 += ks1; x1 += ks2 + 1u;
  TFR(17) TFR(29) TFR(16) TFR(24) x0 += ks2; x1 += ks0 + 2u;
  TFR(13) TFR(15) TFR(26) TFR(6)  x0 += ks0; x1 += ks1 + 3u;
  TFR(17) TFR(29) TFR(16) TFR(24) x0 += ks1; x1 += ks2 + 4u;
  TFR(13) TFR(15) TFR(26) TFR(6)  x0 += ks2; x1 += ks0 + 5u;
#undef TFR
  o0 = x0; o1 = x1;
}

__device__ inline float gelu_fast(float x) {
  const float ax = __builtin_fabsf(x);
  const float ay = 0.70710678118654752f * ax;
  const float t = __builtin_amdgcn_rcpf(fmaf(0.3275911f, ay, 1.0f));
  float p = fmaf(1.061405429f, t, -1.453152027f);
  p = fmaf(p, t, 1.421413741f);
  p = fmaf(p, t, -0.284496736f);
  p = fmaf(p, t, 0.254829592f);
  p *= t;
  const float e = __expf(-ay * ay);
  const float erfv = fmaf(-p, e, 1.0f);
  return fmaf(0.5f * ax, erfv, 0.5f * x);
}

// ---- bilinear upsample 8x8 -> 1024x1024, NHWC f16 out ----
__global__ void init_kernel(const float* __restrict__ seed, _Float16* __restrict__ dst) {
  int p = blockIdx.x * blockDim.x + threadIdx.x;
  if (p >= HH * WW) return;
  int y = p >> 10, x = p & 1023;
  float fy = (y + 0.5f) * (8.0f / HH) - 0.5f;
  float fx = (x + 0.5f) * (8.0f / WW) - 0.5f;
  int y0 = (int)floorf(fy); float wy = fy - (float)y0;
  int x0 = (int)floorf(fx); float wx = fx - (float)x0;
  int y0c = min(max(y0, 0), 7), y1c = min(max(y0 + 1, 0), 7);
  int x0c = min(max(x0, 0), 7), x1c = min(max(x0 + 1, 0), 7);
  f16x8 v;
#pragma unroll
  for (int c = 0; c < SD; ++c) {
    const float* s = seed + c * 64;
    float v00 = s[y0c * 8 + x0c], v01 = s[y0c * 8 + x1c];
    float v10 = s[y1c * 8 + x0c], v11 = s[y1c * 8 + x1c];
    float v0 = v00 + (v01 - v00) * wx;
    float v1 = v10 + (v11 - v10) * wx;
    v[c] = (_Float16)(v0 + (v1 - v0) * wy);
  }
  *(f16x8*)(dst + (size_t)p * 8) = v;
}

// ---- pack W1 (A-operand frags) and W2 (B-operand, k''-order) ----
__global__ void prep_kernel(const float* __restrict__ W1, const float* __restrict__ W2,
                            _Float16* __restrict__ w1f, _Float16* __restrict__ w2f) {
  int tid = threadIdx.x;
  for (int i = tid; i < 2 * 3 * 64; i += 256) {
    int nt = i / 192, rem = i % 192;
    int kc = rem / 64, lane = rem % 64;
    int n = nt * 16 + (lane & 15);
    int tap = kc * 4 + (lane >> 4);
#pragma unroll
    for (int j = 0; j < 8; ++j) {
      float v = (tap < 9) ? W1[(n * SD + j) * 9 + tap] : 0.0f;
      w1f[i * 8 + j] = (_Float16)v;
    }
  }
  if (tid < 64) {
    int n = tid & 15, qk = tid >> 4;
#pragma unroll
    for (int jj = 0; jj < 8; ++jj) {
      int ch = qk * 4 + (jj & 3) + ((jj >> 2) << 4);
      float v = (n < 8) ? W2[n * 32 + ch] : 0.0f;
      w2f[tid * 8 + jj] = (_Float16)v;
    }
  }
}

// ---- fused double NCA step ----
__global__ __launch_bounds__(256) void step2_kernel(
    const _Float16* __restrict__ src, _Float16* __restrict__ dst,
    const _Float16* __restrict__ w1f, const _Float16* __restrict__ w2f,
    const float* __restrict__ b1, const float* __restrict__ b2,
    uint32_t k0a, uint32_t k1a, uint32_t k0b, uint32_t k1b) {
  __shared__ _Float16 tileA[20 * SWA * SD];   // 11520 B
  __shared__ _Float16 tileB[NA * SD];         // 9792 B  (18x34, x_{i+1})
  __shared__ _Float16 dxw[NA * SD];           // 9792 B  (dx scatter, reused A then B)

  const int tid = threadIdx.x;
  const int bx = blockIdx.x, by = blockIdx.y;
  const int lane = tid & 63, w = tid >> 6;
  const int m = lane & 15, q = lane >> 4;

  // ---- weight fragments + biases ----
  f16x8 af[2][3];
#pragma unroll
  for (int nt = 0; nt < 2; ++nt)
#pragma unroll
    for (int kc = 0; kc < 3; ++kc)
      af[nt][kc] = *(const f16x8*)(w1f + ((nt * 3 + kc) * 64 + lane) * 8);
  const f16x8 w2fr = *(const f16x8*)(w2f + lane * 8);
  const f32x4 b1q0 = *(const f32x4*)(b1 + q * 4);
  const f32x4 b1q1 = *(const f32x4*)(b1 + 16 + q * 4);
  const float b2v = b2[m & 7];

  // per-lane tap offsets (taps 9..11 are zero-weight rows; clamp addr)
  int offA[3], offB[3];
#pragma unroll
  for (int kc = 0; kc < 3; ++kc) {
    int t = kc * 4 + q; if (t > 8) t = 0;
    int ady = t / 3, adx = t - (t / 3) * 3;
    offA[kc] = (ady * SWA + adx) * 8;
    offB[kc] = (ady * SWB + adx) * 8;
  }

  // ---- stage halo-2 f16 tile: rows by*16-2.., cols bx*32-2.. (zero outside) ----
  for (int i = tid; i < 20 * SWA; i += 256) {
    int ly = i / SWA, lx = i - (i / SWA) * SWA;
    int gy = by * TY + ly - 2, gx = bx * TX + lx - 2;
    u32x4 v = {0u, 0u, 0u, 0u};
    if ((unsigned)gy < HH && (unsigned)gx < WW)
      v = *(const u32x4*)(src + (size_t)(gy * WW + gx) * 8);
    *(u32x4*)&tileA[i * 8] = v;
  }

  // ---- step-B masks for this thread's 2 update pixels (wave-local) ----
  float maskB[2];
#pragma unroll
  for (int half = 0; half < 2; ++half) {
    const int p = w * 128 + half * 64 + lane;
    const uint32_t gp = (uint32_t)((by * TY + (p >> 5)) * WW + bx * TX + (p & 31));
    uint32_t r0, r1;
    tf2x32(k0b, k1b, 0u, gp, r0, r1);
    maskB[half] = (((r0 ^ r1) >> 9) > 0x400000u) ? 0.1f : 0.0f;
  }
  __syncthreads();

  // ---- step A: conv over 18x34 domain -> dxw ----
  for (int gi = 0; gi < 10; ++gi) {
    const int G = w * 10 + gi;            // group 0..39 (>=39: fully OOB, writes skipped)
    const int p = G * 16 + m;             // A-domain pixel of this lane
    const int r = (p * 241) >> 13;        // p/34 (exact for p<~650)
    const int c = p - r * 34;
    const int base = (r * SWA + c) * 8;
    f32x4 acc0 = b1q0, acc1 = b1q1;
#pragma unroll
    for (int kc = 0; kc < 3; ++kc) {
      const f16x8 bfrag = *(const f16x8*)&tileA[base + offA[kc]];
      acc0 = __builtin_amdgcn_mfma_f32_16x16x32_f16(af[0][kc], bfrag, acc0, 0, 0, 0);
      acc1 = __builtin_amdgcn_mfma_f32_16x16x32_f16(af[1][kc], bfrag, acc1, 0, 0, 0);
    }
    u32x4 a2d;
    {
      float g0 = gelu_fast(acc0[0]), g1 = gelu_fast(acc0[1]);
      float g2 = gelu_fast(acc0[2]), g3 = gelu_fast(acc0[3]);
      float g4 = gelu_fast(acc1[0]), g5 = gelu_fast(acc1[1]);
      float g6 = gelu_fast(acc1[2]), g7 = gelu_fast(acc1[3]);
      a2d[0] = __builtin_bit_cast(uint32_t, __builtin_amdgcn_cvt_pkrtz(g0, g1));
      a2d[1] = __builtin_bit_cast(uint32_t, __builtin_amdgcn_cvt_pkrtz(g2, g3));
      a2d[2] = __builtin_bit_cast(uint32_t, __builtin_amdgcn_cvt_pkrtz(g4, g5));
      a2d[3] = __builtin_bit_cast(uint32_t, __builtin_amdgcn_cvt_pkrtz(g6, g7));
    }
    const f16x8 a2 = __builtin_bit_cast(f16x8, a2d);
    f32x4 acc2 = {b2v, b2v, b2v, b2v};
    acc2 = __builtin_amdgcn_mfma_f32_16x16x32_f16(a2, w2fr, acc2, 0, 0, 0);
    const int pp = G * 16 + q * 4;        // pixel of reg 0 (quad-aligned; NA%4==0)
    if (m < 8 && pp < NA) {
      _Float16* wp = &dxw[pp * 8 + m];
      wp[0]  = (_Float16)acc2[0];
      wp[8]  = (_Float16)acc2[1];
      wp[16] = (_Float16)acc2[2];
      wp[24] = (_Float16)acc2[3];
    }
  }
  __syncthreads();

  // ---- assemble x_{i+1} into tileB (zero out-of-image ring = SAME padding) ----
#pragma unroll
  for (int k = 0; k < 3; ++k) {
    const int p = tid + k * 256;
    if (p < NA) {
      const int r = (p * 241) >> 13;
      const int c = p - r * 34;
      const int gy = by * TY + r - 1, gx = bx * TX + c - 1;
      const bool in = ((unsigned)gy < HH) && ((unsigned)gx < WW);
      float mk = 0.0f;
      if (in) {
        uint32_t r0, r1;
        tf2x32(k0a, k1a, 0u, (uint32_t)(gy * WW + gx), r0, r1);
        mk = (((r0 ^ r1) >> 9) > 0x400000u) ? 0.1f : 0.0f;
      }
      const f16x8 xi = *(const f16x8*)&tileA[((r + 1) * SWA + c + 1) * 8];
      const f16x8 dx = *(const f16x8*)&dxw[p * 8];
      f16x8 xo;
#pragma unroll
      for (int j = 0; j < 8; ++j)
        xo[j] = in ? (_Float16)fmaf((float)dx[j], mk, (float)xi[j]) : (_Float16)0.0f;
      *(f16x8*)&tileB[p * 8] = xo;
    }
  }
  __syncthreads();

  // ---- step B: conv over 16x32 output -> dxw (wave-local reuse) ----
  for (int gi = 0; gi < 8; ++gi) {
    const int G = w * 8 + gi;             // wave-local: wave w covers pixels 128w..128w+127
    const int p = G * 16 + m;             // output pixel 0..511
    const int r = p >> 5, c = p & 31;
    const int base = (r * SWB + c) * 8;
    f32x4 acc0 = b1q0, acc1 = b1q1;
#pragma unroll
    for (int kc = 0; kc < 3; ++kc) {
      const f16x8 bfrag = *(const f16x8*)&tileB[base + offB[kc]];
      acc0 = __builtin_amdgcn_mfma_f32_16x16x32_f16(af[0][kc], bfrag, acc0, 0, 0, 0);
      acc1 = __builtin_amdgcn_mfma_f32_16x16x32_f16(af[1][kc], bfrag, acc1, 0, 0, 0);
    }
    u32x4 a2d;
    {
      float g0 = gelu_fast(acc0[0]), g1 = gelu_fast(acc0[1]);
      float g2 = gelu_fast(acc0[2]), g3 = gelu_fast(acc0[3]);
      float g4 = gelu_fast(acc1[0]), g5 = gelu_fast(acc1[1]);
      float g6 = gelu_fast(acc1[2]), g7 = gelu_fast(acc1[3]);
      a2d[0] = __builtin_bit_cast(uint32_t, __builtin_amdgcn_cvt_pkrtz(g0, g1));
      a2d[1] = __builtin_bit_cast(uint32_t, __builtin_amdgcn_cvt_pkrtz(g2, g3));
      a2d[2] = __builtin_bit_cast(uint32_t, __builtin_amdgcn_cvt_pkrtz(g4, g5));
      a2d[3] = __builtin_bit_cast(uint32_t, __builtin_amdgcn_cvt_pkrtz(g6, g7));
    }
    const f16x8 a2 = __builtin_bit_cast(f16x8, a2d);
    f32x4 acc2 = {b2v, b2v, b2v, b2v};
    acc2 = __builtin_amdgcn_mfma_f32_16x16x32_f16(a2, w2fr, acc2, 0, 0, 0);
    if (m < 8) {
      _Float16* wp = &dxw[(G * 16 + q * 4) * 8 + m];
      wp[0]  = (_Float16)acc2[0];
      wp[8]  = (_Float16)acc2[1];
      wp[16] = (_Float16)acc2[2];
      wp[24] = (_Float16)acc2[3];
    }
  }

  // ---- wave-local coalesced update: x_{i+2} = x_{i+1} + dx*(0.1*maskB) -> dst ----
#pragma unroll
  for (int half = 0; half < 2; ++half) {
    const int pw = half * 64 + lane;
    const int p = w * 128 + pw;
    const int py = p >> 5, px = p & 31;
    const uint32_t gp = (uint32_t)((by * TY + py) * WW + bx * TX + px);
    const float mk = maskB[half];
    const f16x8 xi = *(const f16x8*)&tileB[((py + 1) * SWB + px + 1) * 8];
    const f16x8 dx = *(const f16x8*)&dxw[p * 8];
    f16x8 xo;
#pragma unroll
    for (int j = 0; j < 8; ++j)
      xo[j] = (_Float16)fmaf((float)dx[j], mk, (float)xi[j]);
    *(f16x8*)(dst + (size_t)gp * 8) = xo;
  }
}

// ---- projection: out[p] = bp + sum_c x[p][c]*Wp[c] ----
__global__ void proj_kernel(const _Float16* __restrict__ x,
                            const float* __restrict__ Wp,
                            const float* __restrict__ bp,
                            float* __restrict__ out) {
  int p = blockIdx.x * blockDim.x + threadIdx.x;
  if (p >= HH * WW) return;
  const f16x8 xv = *(const f16x8*)(x + (size_t)p * 8);
  float acc = bp[0];
#pragma unroll
  for (int c = 0; c < SD; ++c) acc = fmaf((float)xv[c], Wp[c], acc);
  out[p] = acc;
}

extern "C" void kernel_launch(void* const* d_in, const int* in_sizes, int n_in,
                              void* d_out, int out_size, void* d_ws, size_t ws_size,
                              hipStream_t stream) {
  (void)in_sizes; (void)n_in; (void)out_size; (void)ws_size;
  const float* seed = (const float*)d_in[0];
  const float* W1   = (const float*)d_in[1];
  const float* b1   = (const float*)d_in[2];
  const float* W2   = (const float*)d_in[3];
  const float* b2   = (const float*)d_in[4];
  const float* Wp   = (const float*)d_in[5];
  const float* bp   = (const float*)d_in[6];
  float* out  = (float*)d_out;
  _Float16* buf0 = (_Float16*)d_ws;
  _Float16* buf1 = buf0 + (size_t)SD * HH * WW;
  _Float16* w1f  = buf1 + (size_t)SD * HH * WW;
  _Float16* w2f  = w1f + 2 * 3 * 64 * 8;

  // 64 subkeys of jax.random.split(jax.random.key(42), 64) (raw pairs, no xor)
  uint32_t ka[64], kb[64];
  for (int i = 0; i < 64; ++i) tf2x32(0u, 42u, 0u, (uint32_t)i, ka[i], kb[i]);

  hipLaunchKernelGGL(prep_kernel, dim3(1), dim3(256), 0, stream, W1, W2, w1f, w2f);
  hipLaunchKernelGGL(init_kernel, dim3((HH * WW) / 256), dim3(256), 0, stream, seed, buf0);

  dim3 grid(WW / TX, HH / TY);
  _Float16* s = buf0; _Float16* d = buf1;
  for (int i = 0; i < 64; i += 2) {
    hipLaunchKernelGGL(step2_kernel, grid, dim3(256), 0, stream,
                       s, d, w1f, w2f, b1, b2, ka[i], kb[i], ka[i + 1], kb[i + 1]);
    _Float16* t = s; s = d; d = t;
  }
  hipLaunchKernelGGL(proj_kernel, dim3((HH * WW) / 256), dim3(256), 0, stream,
                     s, Wp, bp, out);
}

// Round 10
// 1676.950 us; speedup vs baseline: 1.1310x; 1.0326x over previous
//
#include <hip/hip_runtime.h>
#include <cstdint>
#include <cstddef>

// NCA, 2 steps fused per launch. State: NHWC f16, double-buffered in d_ws.
// Per block (output 16x32): stage 20x36 halo-2 tile (tileA) -> step A conv over the
// 18x34 ring-extended domain (ring recomputed bit-identically by neighbors; no seams)
// -> assemble x_{i+1} IN PLACE into tileA's center (OOB ring stays 0 = SAME padding)
// -> step B conv over 16x32 -> masked update -> dst. 3 barriers / 2 steps.
// Convs: mfma_f32_16x16x32_f16 operand-swapped (A=weights, B=pixels):
//   conv3x3 D: row(q*4+reg)=hidden-ch, col(lane&15)=pixel; K-order k=tap*8+c.
//   gelu'd accs pack directly into conv1x1 A-operand (k''-order W2, no LDS transpose).
//   conv1x1 D: row=pixel-in-group, col=out-ch -> wave-local dxw scatter.
// Updates in packed f16 (v_pk_fma_f16): x' = dx*(0.1*mask) + x.
// gelu: exact erf via A&S 7.1.26 branchless (|err|<=1.5e-7).
// PRNG: jax threefry2x32 partitionable: subkey[i]=raw pair tf2x32((0,42),(0,i));
// bits[p]=o0^o1 of tf2x32(subkey,(0,p)); mask = (bits>>9) > 2^22.

#define HH 1024
#define WW 1024
#define SD 8
#define TX 32
#define TY 16
#define NA 612           // step-A domain: 18*34
#define SWA 36           // tileA row stride (pixels)

typedef _Float16 f16x8 __attribute__((ext_vector_type(8)));
typedef float f32x4 __attribute__((ext_vector_type(4)));
typedef uint32_t u32x4 __attribute__((ext_vector_type(4)));

__host__ __device__ inline uint32_t rotl32(uint32_t x, int n) {
  return (x << n) | (x >> (32 - n));
}

__host__ __device__ inline void tf2x32(uint32_t k0, uint32_t k1,
                                       uint32_t x0, uint32_t x1,
                                       uint32_t& o0, uint32_t& o1) {
  uint32_t ks0 = k0, ks1 = k1, ks2 = k0 ^ k1 ^ 0x1BD11BDAu;
  x0 += ks0; x1 += ks1;
#define TFR(r) { x0 += x1; x1 = rotl32(x1, (r)); x1 ^= x0; }
  TFR(13) TFR(15) TFR(26) TFR(6)  x0 += ks1; x1 += ks2 + 1u;
  TFR(17) TFR(29) TFR(16) TFR(24) x0 += ks2; x1 += ks0 + 2u;
  TFR(13) TFR(15) TFR(26) TFR(6)  x0 += ks0; x1 += ks1 + 3u;
  TFR(17) TFR(29) TFR(16) TFR(24) x0 += ks1; x1 += ks2 + 4u;
  TFR(13) TFR(15) TFR(26) TFR(6)  x0 += ks2; x1 += ks0 + 5u;
#undef TFR
  o0 = x0; o1 = x1;
}

__device__ inline float gelu_fast(float x) {
  const float ax = __builtin_fabsf(x);
  const float ay = 0.70710678118654752f * ax;
  const float t = __builtin_amdgcn_rcpf(fmaf(0.3275911f, ay, 1.0f));
  float p = fmaf(1.061405429f, t, -1.453152027f);
  p = fmaf(p, t, 1.421413741f);
  p = fmaf(p, t, -0.284496736f);
  p = fmaf(p, t, 0.254829592f);
  p *= t;
  const float e = __expf(-ay * ay);
  const float erfv = fmaf(-p, e, 1.0f);
  return fmaf(0.5f * ax, erfv, 0.5f * x);
}

// ---- bilinear upsample 8x8 -> 1024x1024, NHWC f16 out ----
__global__ void init_kernel(const float* __restrict__ seed, _Float16* __restrict__ dst) {
  int p = blockIdx.x * blockDim.x + threadIdx.x;
  if (p >= HH * WW) return;
  int y = p >> 10, x = p & 1023;
  float fy = (y + 0.5f) * (8.0f / HH) - 0.5f;
  float fx = (x + 0.5f) * (8.0f / WW) - 0.5f;
  int y0 = (int)floorf(fy); float wy = fy - (float)y0;
  int x0 = (int)floorf(fx); float wx = fx - (float)x0;
  int y0c = min(max(y0, 0), 7), y1c = min(max(y0 + 1, 0), 7);
  int x0c = min(max(x0, 0), 7), x1c = min(max(x0 + 1, 0), 7);
  f16x8 v;
#pragma unroll
  for (int c = 0; c < SD; ++c) {
    const float* s = seed + c * 64;
    float v00 = s[y0c * 8 + x0c], v01 = s[y0c * 8 + x1c];
    float v10 = s[y1c * 8 + x0c], v11 = s[y1c * 8 + x1c];
    float v0 = v00 + (v01 - v00) * wx;
    float v1 = v10 + (v11 - v10) * wx;
    v[c] = (_Float16)(v0 + (v1 - v0) * wy);
  }
  *(f16x8*)(dst + (size_t)p * 8) = v;
}

// ---- pack W1 (A-operand frags) and W2 (B-operand, k''-order) ----
__global__ void prep_kernel(const float* __restrict__ W1, const float* __restrict__ W2,
                            _Float16* __restrict__ w1f, _Float16* __restrict__ w2f) {
  int tid = threadIdx.x;
  for (int i = tid; i < 2 * 3 * 64; i += 256) {
    int nt = i / 192, rem = i % 192;
    int kc = rem / 64, lane = rem % 64;
    int n = nt * 16 + (lane & 15);
    int tap = kc * 4 + (lane >> 4);
#pragma unroll
    for (int j = 0; j < 8; ++j) {
      float v = (tap < 9) ? W1[(n * SD + j) * 9 + tap] : 0.0f;
      w1f[i * 8 + j] = (_Float16)v;
    }
  }
  if (tid < 64) {
    int n = tid & 15, qk = tid >> 4;
#pragma unroll
    for (int jj = 0; jj < 8; ++jj) {
      int ch = qk * 4 + (jj & 3) + ((jj >> 2) << 4);
      float v = (n < 8) ? W2[n * 32 + ch] : 0.0f;
      w2f[tid * 8 + jj] = (_Float16)v;
    }
  }
}

// ---- fused double NCA step (in-place second tile, packed-f16 updates) ----
__global__ __launch_bounds__(256) void step2_kernel(
    const _Float16* __restrict__ src, _Float16* __restrict__ dst,
    const _Float16* __restrict__ w1f, const _Float16* __restrict__ w2f,
    const float* __restrict__ b1, const float* __restrict__ b2,
    uint32_t k0a, uint32_t k1a, uint32_t k0b, uint32_t k1b) {
  __shared__ _Float16 tileA[20 * SWA * SD];   // 11520 B (state tile; x_{i+1} in center)
  __shared__ _Float16 dxw[NA * SD];           // 9792 B  (dx scatter, reused A then B)

  const int tid = threadIdx.x;
  const int bx = blockIdx.x, by = blockIdx.y;
  const int lane = tid & 63, w = tid >> 6;
  const int m = lane & 15, q = lane >> 4;

  // ---- weight fragments + biases ----
  f16x8 af[2][3];
#pragma unroll
  for (int nt = 0; nt < 2; ++nt)
#pragma unroll
    for (int kc = 0; kc < 3; ++kc)
      af[nt][kc] = *(const f16x8*)(w1f + ((nt * 3 + kc) * 64 + lane) * 8);
  const f16x8 w2fr = *(const f16x8*)(w2f + lane * 8);
  const f32x4 b1q0 = *(const f32x4*)(b1 + q * 4);
  const f32x4 b1q1 = *(const f32x4*)(b1 + 16 + q * 4);
  const float b2v = b2[m & 7];

  // per-lane tap offsets (taps 9..11 are zero-weight rows; clamp addr)
  int off[3];
#pragma unroll
  for (int kc = 0; kc < 3; ++kc) {
    int t = kc * 4 + q; if (t > 8) t = 0;
    off[kc] = ((t / 3) * SWA + (t % 3)) * 8;
  }

  // ---- stage halo-2 f16 tile: rows by*16-2.., cols bx*32-2.. (zero outside) ----
  for (int i = tid; i < 20 * SWA; i += 256) {
    int ly = i / SWA, lx = i - (i / SWA) * SWA;
    int gy = by * TY + ly - 2, gx = bx * TX + lx - 2;
    u32x4 v = {0u, 0u, 0u, 0u};
    if ((unsigned)gy < HH && (unsigned)gx < WW)
      v = *(const u32x4*)(src + (size_t)(gy * WW + gx) * 8);
    *(u32x4*)&tileA[i * 8] = v;
  }

  // ---- step-B masks for this thread's 2 update pixels (wave-local) ----
  _Float16 maskB[2];
#pragma unroll
  for (int half = 0; half < 2; ++half) {
    const int p = w * 128 + half * 64 + lane;
    const uint32_t gp = (uint32_t)((by * TY + (p >> 5)) * WW + bx * TX + (p & 31));
    uint32_t r0, r1;
    tf2x32(k0b, k1b, 0u, gp, r0, r1);
    maskB[half] = (((r0 ^ r1) >> 9) > 0x400000u) ? (_Float16)0.1f : (_Float16)0.0f;
  }
  __syncthreads();

  // ---- step A: conv over 18x34 domain -> dxw ----
  for (int gi = 0; gi < 10; ++gi) {
    const int G = w * 10 + gi;            // group 0..39 (tail lanes read in-LDS garbage,
    const int p = G * 16 + m;             //  results discarded by pp<NA guard)
    const int r = (p * 241) >> 13;        // p/34 (exact for p < ~650)
    const int c = p - r * 34;
    const int base = (r * SWA + c) * 8;
    f32x4 acc0 = b1q0, acc1 = b1q1;
#pragma unroll
    for (int kc = 0; kc < 3; ++kc) {
      const f16x8 bfrag = *(const f16x8*)&tileA[base + off[kc]];
      acc0 = __builtin_amdgcn_mfma_f32_16x16x32_f16(af[0][kc], bfrag, acc0, 0, 0, 0);
      acc1 = __builtin_amdgcn_mfma_f32_16x16x32_f16(af[1][kc], bfrag, acc1, 0, 0, 0);
    }
    u32x4 a2d;
    {
      float g0 = gelu_fast(acc0[0]), g1 = gelu_fast(acc0[1]);
      float g2 = gelu_fast(acc0[2]), g3 = gelu_fast(acc0[3]);
      float g4 = gelu_fast(acc1[0]), g5 = gelu_fast(acc1[1]);
      float g6 = gelu_fast(acc1[2]), g7 = gelu_fast(acc1[3]);
      a2d[0] = __builtin_bit_cast(uint32_t, __builtin_amdgcn_cvt_pkrtz(g0, g1));
      a2d[1] = __builtin_bit_cast(uint32_t, __builtin_amdgcn_cvt_pkrtz(g2, g3));
      a2d[2] = __builtin_bit_cast(uint32_t, __builtin_amdgcn_cvt_pkrtz(g4, g5));
      a2d[3] = __builtin_bit_cast(uint32_t, __builtin_amdgcn_cvt_pkrtz(g6, g7));
    }
    const f16x8 a2 = __builtin_bit_cast(f16x8, a2d);
    f32x4 acc2 = {b2v, b2v, b2v, b2v};
    acc2 = __builtin_amdgcn_mfma_f32_16x16x32_f16(a2, w2fr, acc2, 0, 0, 0);
    const int pp = G * 16 + q * 4;
    if (m < 8 && pp < NA) {
      _Float16* wp = &dxw[pp * 8 + m];
      wp[0]  = (_Float16)acc2[0];
      wp[8]  = (_Float16)acc2[1];
      wp[16] = (_Float16)acc2[2];
      wp[24] = (_Float16)acc2[3];
    }
  }
  __syncthreads();

  // ---- assemble x_{i+1} IN PLACE into tileA center (element-wise; OOB: xi=0,mk=0 -> 0) ----
#pragma unroll
  for (int k = 0; k < 3; ++k) {
    const int p = tid + k * 256;
    if (p < NA) {
      const int r = (p * 241) >> 13;
      const int c = p - r * 34;
      const int gy = by * TY + r - 1, gx = bx * TX + c - 1;
      _Float16 mk = (_Float16)0.0f;
      if (((unsigned)gy < HH) && ((unsigned)gx < WW)) {
        uint32_t r0, r1;
        tf2x32(k0a, k1a, 0u, (uint32_t)(gy * WW + gx), r0, r1);
        mk = (((r0 ^ r1) >> 9) > 0x400000u) ? (_Float16)0.1f : (_Float16)0.0f;
      }
      _Float16* xp = &tileA[((r + 1) * SWA + (c + 1)) * 8];
      const f16x8 xi = *(const f16x8*)xp;
      const f16x8 dx = *(const f16x8*)&dxw[p * 8];
      const f16x8 mk8 = {mk, mk, mk, mk, mk, mk, mk, mk};
      const f16x8 xo = dx * mk8 + xi;     // v_pk_fma_f16 x4
      *(f16x8*)xp = xo;
    }
  }
  __syncthreads();

  // ---- step B: conv over 16x32 output (tileA center, offset (1,1)) -> dxw ----
  for (int gi = 0; gi < 8; ++gi) {
    const int G = w * 8 + gi;             // wave w covers output pixels 128w..128w+127
    const int p = G * 16 + m;
    const int r = p >> 5, c = p & 31;
    const int base = ((r + 1) * SWA + (c + 1)) * 8;
    f32x4 acc0 = b1q0, acc1 = b1q1;
#pragma unroll
    for (int kc = 0; kc < 3; ++kc) {
      const f16x8 bfrag = *(const f16x8*)&tileA[base + off[kc]];
      acc0 = __builtin_amdgcn_mfma_f32_16x16x32_f16(af[0][kc], bfrag, acc0, 0, 0, 0);
      acc1 = __builtin_amdgcn_mfma_f32_16x16x32_f16(af[1][kc], bfrag, acc1, 0, 0, 0);
    }
    u32x4 a2d;
    {
      float g0 = gelu_fast(acc0[0]), g1 = gelu_fast(acc0[1]);
      float g2 = gelu_fast(acc0[2]), g3 = gelu_fast(acc0[3]);
      float g4 = gelu_fast(acc1[0]), g5 = gelu_fast(acc1[1]);
      float g6 = gelu_fast(acc1[2]), g7 = gelu_fast(acc1[3]);
      a2d[0] = __builtin_bit_cast(uint32_t, __builtin_amdgcn_cvt_pkrtz(g0, g1));
      a2d[1] = __builtin_bit_cast(uint32_t, __builtin_amdgcn_cvt_pkrtz(g2, g3));
      a2d[2] = __builtin_bit_cast(uint32_t, __builtin_amdgcn_cvt_pkrtz(g4, g5));
      a2d[3] = __builtin_bit_cast(uint32_t, __builtin_amdgcn_cvt_pkrtz(g6, g7));
    }
    const f16x8 a2 = __builtin_bit_cast(f16x8, a2d);
    f32x4 acc2 = {b2v, b2v, b2v, b2v};
    acc2 = __builtin_amdgcn_mfma_f32_16x16x32_f16(a2, w2fr, acc2, 0, 0, 0);
    if (m < 8) {
      _Float16* wp = &dxw[(G * 16 + q * 4) * 8 + m];
      wp[0]  = (_Float16)acc2[0];
      wp[8]  = (_Float16)acc2[1];
      wp[16] = (_Float16)acc2[2];
      wp[24] = (_Float16)acc2[3];
    }
  }

  // ---- wave-local coalesced update: x_{i+2} = x_{i+1} + dx*(0.1*maskB) -> dst ----
#pragma unroll
  for (int half = 0; half < 2; ++half) {
    const int pw = half * 64 + lane;
    const int p = w * 128 + pw;
    const int py = p >> 5, px = p & 31;
    const uint32_t gp = (uint32_t)((by * TY + py) * WW + bx * TX + px);
    const _Float16 mk = maskB[half];
    const f16x8 xi = *(const f16x8*)&tileA[((py + 2) * SWA + (px + 2)) * 8];
    const f16x8 dx = *(const f16x8*)&dxw[p * 8];
    const f16x8 mk8 = {mk, mk, mk, mk, mk, mk, mk, mk};
    const f16x8 xo = dx * mk8 + xi;       // v_pk_fma_f16 x4
    *(f16x8*)(dst + (size_t)gp * 8) = xo;
  }
}

// ---- projection: out[p] = bp + sum_c x[p][c]*Wp[c] ----
__global__ void proj_kernel(const _Float16* __restrict__ x,
                            const float* __restrict__ Wp,
                            const float* __restrict__ bp,
                            float* __restrict__ out) {
  int p = blockIdx.x * blockDim.x + threadIdx.x;
  if (p >= HH * WW) return;
  const f16x8 xv = *(const f16x8*)(x + (size_t)p * 8);
  float acc = bp[0];
#pragma unroll
  for (int c = 0; c < SD; ++c) acc = fmaf((float)xv[c], Wp[c], acc);
  out[p] = acc;
}

extern "C" void kernel_launch(void* const* d_in, const int* in_sizes, int n_in,
                              void* d_out, int out_size, void* d_ws, size_t ws_size,
                              hipStream_t stream) {
  (void)in_sizes; (void)n_in; (void)out_size; (void)ws_size;
  const float* seed = (const float*)d_in[0];
  const float* W1   = (const float*)d_in[1];
  const float* b1   = (const float*)d_in[2];
  const float* W2   = (const float*)d_in[3];
  const float* b2   = (const float*)d_in[4];
  const float* Wp   = (const float*)d_in[5];
  const float* bp   = (const float*)d_in[6];
  float* out  = (float*)d_out;
  _Float16* buf0 = (_Float16*)d_ws;
  _Float16* buf1 = buf0 + (size_t)SD * HH * WW;
  _Float16* w1f  = buf1 + (size_t)SD * HH * WW;
  _Float16* w2f  = w1f + 2 * 3 * 64 * 8;

  // 64 subkeys of jax.random.split(jax.random.key(42), 64) (raw pairs, no xor)
  uint32_t ka[64], kb[64];
  for (int i = 0; i < 64; ++i) tf2x32(0u, 42u, 0u, (uint32_t)i, ka[i], kb[i]);

  hipLaunchKernelGGL(prep_kernel, dim3(1), dim3(256), 0, stream, W1, W2, w1f, w2f);
  hipLaunchKernelGGL(init_kernel, dim3((HH * WW) / 256), dim3(256), 0, stream, seed, buf0);

  dim3 grid(WW / TX, HH / TY);
  _Float16* s = buf0; _Float16* d = buf1;
  for (int i = 0; i < 64; i += 2) {
    hipLaunchKernelGGL(step2_kernel, grid, dim3(256), 0, stream,
                       s, d, w1f, w2f, b1, b2, ka[i], kb[i], ka[i + 1], kb[i + 1]);
    _Float16* t = s; s = d; d = t;
  }
  hipLaunchKernelGGL(proj_kernel, dim3((HH * WW) / 256), dim3(256), 0, stream,
                     s, Wp, bp, out);
}

// Round 11
// 1449.910 us; speedup vs baseline: 1.3081x; 1.1566x over previous
//
#include <hip/hip_runtime.h>
#include <cstdint>
#include <cstddef>

// NCA, 2 steps fused per launch; each block processes TWO tiles (tail-free: 1024 blocks
// x 2 tiles = 2048 tiles, 4 blocks/CU full-duration). State: NHWC f16, double-buffered.
// Per tile (output 16x32): stage 20x36 halo-2 tileA -> step A conv over 18x34 domain
// (ring recomputed bit-identically by neighbors; no seams) -> assemble x_{i+1} in place
// -> step B conv over 16x32 -> masked update -> dst.
// Convs: mfma_f32_16x16x32_f16 operand-swapped (A=weights, B=pixels); gelu'd accs feed
// conv1x1 A-operand directly (k''-order W2). dx scatter in padded LDS (40 f16 per
// 4-pixel row -> conflict-free quad writes). Updates in packed f16.
// gelu: tanh form x*(1-1/(1+e^{2w})), 2w = x*(1.5957691 + 0.0713548 x^2), |err|~1.5e-4.
// PRNG: jax threefry2x32 partitionable: subkey[i]=raw pair tf2x32((0,42),(0,i));
// bits[p]=o0^o1 of tf2x32(subkey,(0,p)); mask = (bits>>9) > 2^22.

#define HH 1024
#define WW 1024
#define SD 8
#define TX 32
#define TY 16
#define NA 612           // step-A domain: 18*34
#define SWA 36           // tileA row stride (pixels)
#define DXROWS 154       // ceil(612/4) rows + spare

typedef _Float16 f16x8 __attribute__((ext_vector_type(8)));
typedef float f32x4 __attribute__((ext_vector_type(4)));
typedef uint32_t u32x4 __attribute__((ext_vector_type(4)));

__host__ __device__ inline uint32_t rotl32(uint32_t x, int n) {
  return (x << n) | (x >> (32 - n));
}

__host__ __device__ inline void tf2x32(uint32_t k0, uint32_t k1,
                                       uint32_t x0, uint32_t x1,
                                       uint32_t& o0, uint32_t& o1) {
  uint32_t ks0 = k0, ks1 = k1, ks2 = k0 ^ k1 ^ 0x1BD11BDAu;
  x0 += ks0; x1 += ks1;
#define TFR(r) { x0 += x1; x1 = rotl32(x1, (r)); x1 ^= x0; }
  TFR(13) TFR(15) TFR(26) TFR(6)  x0 += ks1; x1 += ks2 + 1u;
  TFR(17) TFR(29) TFR(16) TFR(24) x0 += ks2; x1 += ks0 + 2u;
  TFR(13) TFR(15) TFR(26) TFR(6)  x0 += ks0; x1 += ks1 + 3u;
  TFR(17) TFR(29) TFR(16) TFR(24) x0 += ks1; x1 += ks2 + 4u;
  TFR(13) TFR(15) TFR(26) TFR(6)  x0 += ks2; x1 += ks0 + 5u;
#undef TFR
  o0 = x0; o1 = x1;
}

// gelu tanh-form: x - x/(1+e^{2w}), 2w = x*(1.5957691 + 0.0713548*x^2).
// 6 full-rate + exp + rcp. |err vs exact erf-gelu| ~1.5e-4. Saturates correctly at +-inf.
__device__ inline float gelu_fast(float x) {
  const float s = x * x;
  const float z = x * fmaf(0.0713548162f, s, 1.5957691216f);
  const float e = __expf(z);
  const float t = __builtin_amdgcn_rcpf(1.0f + e);
  return fmaf(-x, t, x);
}

// ---- bilinear upsample 8x8 -> 1024x1024, NHWC f16 out ----
__global__ void init_kernel(const float* __restrict__ seed, _Float16* __restrict__ dst) {
  int p = blockIdx.x * blockDim.x + threadIdx.x;
  if (p >= HH * WW) return;
  int y = p >> 10, x = p & 1023;
  float fy = (y + 0.5f) * (8.0f / HH) - 0.5f;
  float fx = (x + 0.5f) * (8.0f / WW) - 0.5f;
  int y0 = (int)floorf(fy); float wy = fy - (float)y0;
  int x0 = (int)floorf(fx); float wx = fx - (float)x0;
  int y0c = min(max(y0, 0), 7), y1c = min(max(y0 + 1, 0), 7);
  int x0c = min(max(x0, 0), 7), x1c = min(max(x0 + 1, 0), 7);
  f16x8 v;
#pragma unroll
  for (int c = 0; c < SD; ++c) {
    const float* s = seed + c * 64;
    float v00 = s[y0c * 8 + x0c], v01 = s[y0c * 8 + x1c];
    float v10 = s[y1c * 8 + x0c], v11 = s[y1c * 8 + x1c];
    float v0 = v00 + (v01 - v00) * wx;
    float v1 = v10 + (v11 - v10) * wx;
    v[c] = (_Float16)(v0 + (v1 - v0) * wy);
  }
  *(f16x8*)(dst + (size_t)p * 8) = v;
}

// ---- pack W1 (A-operand frags) and W2 (B-operand, k''-order) ----
__global__ void prep_kernel(const float* __restrict__ W1, const float* __restrict__ W2,
                            _Float16* __restrict__ w1f, _Float16* __restrict__ w2f) {
  int tid = threadIdx.x;
  for (int i = tid; i < 2 * 3 * 64; i += 256) {
    int nt = i / 192, rem = i % 192;
    int kc = rem / 64, lane = rem % 64;
    int n = nt * 16 + (lane & 15);
    int tap = kc * 4 + (lane >> 4);
#pragma unroll
    for (int j = 0; j < 8; ++j) {
      float v = (tap < 9) ? W1[(n * SD + j) * 9 + tap] : 0.0f;
      w1f[i * 8 + j] = (_Float16)v;
    }
  }
  if (tid < 64) {
    int n = tid & 15, qk = tid >> 4;
#pragma unroll
    for (int jj = 0; jj < 8; ++jj) {
      int ch = qk * 4 + (jj & 3) + ((jj >> 2) << 4);
      float v = (n < 8) ? W2[n * 32 + ch] : 0.0f;
      w2f[tid * 8 + jj] = (_Float16)v;
    }
  }
}

// ---- fused double NCA step, 2 tiles per block ----
__global__ __launch_bounds__(256) void step2_kernel(
    const _Float16* __restrict__ src, _Float16* __restrict__ dst,
    const _Float16* __restrict__ w1f, const _Float16* __restrict__ w2f,
    const float* __restrict__ b1, const float* __restrict__ b2,
    uint32_t k0a, uint32_t k1a, uint32_t k0b, uint32_t k1b) {
  __shared__ _Float16 tileA[20 * SWA * SD];   // 11520 B
  __shared__ _Float16 dxw[DXROWS * 40];       // 12320 B, padded: 40 f16 per 4-px row

  const int tid = threadIdx.x;
  const int bx = blockIdx.x;
  const int lane = tid & 63, w = tid >> 6;
  const int m = lane & 15, q = lane >> 4;

  // ---- weight fragments + biases ----
  f16x8 af[2][3];
#pragma unroll
  for (int nt = 0; nt < 2; ++nt)
#pragma unroll
    for (int kc = 0; kc < 3; ++kc)
      af[nt][kc] = *(const f16x8*)(w1f + ((nt * 3 + kc) * 64 + lane) * 8);
  const f16x8 w2fr = *(const f16x8*)(w2f + lane * 8);
  const f32x4 b1q0 = *(const f32x4*)(b1 + q * 4);
  const f32x4 b1q1 = *(const f32x4*)(b1 + 16 + q * 4);
  const float b2v = b2[m & 7];

  // per-lane tap offsets (taps 9..11 are zero-weight rows; clamp addr)
  int off[3];
#pragma unroll
  for (int kc = 0; kc < 3; ++kc) {
    int t = kc * 4 + q; if (t > 8) t = 0;
    off[kc] = ((t / 3) * SWA + (t % 3)) * 8;
  }

  for (int it2 = 0; it2 < 2; ++it2) {
    const int by = blockIdx.y + it2 * 32;   // tile rows: by and by+32
    if (it2) __syncthreads();               // protect tileA/dxw reuse across tiles

    // ---- stage halo-2 f16 tile (zero outside) ----
    for (int i = tid; i < 20 * SWA; i += 256) {
      int ly = i / SWA, lx = i - (i / SWA) * SWA;
      int gy = by * TY + ly - 2, gx = bx * TX + lx - 2;
      u32x4 v = {0u, 0u, 0u, 0u};
      if ((unsigned)gy < HH && (unsigned)gx < WW)
        v = *(const u32x4*)(src + (size_t)(gy * WW + gx) * 8);
      *(u32x4*)&tileA[i * 8] = v;
    }

    // ---- step-B masks for this thread's 2 update pixels (wave-local) ----
    _Float16 maskB[2];
#pragma unroll
    for (int half = 0; half < 2; ++half) {
      const int p = w * 128 + half * 64 + lane;
      const uint32_t gp = (uint32_t)((by * TY + (p >> 5)) * WW + bx * TX + (p & 31));
      uint32_t r0, r1;
      tf2x32(k0b, k1b, 0u, gp, r0, r1);
      maskB[half] = (((r0 ^ r1) >> 9) > 0x400000u) ? (_Float16)0.1f : (_Float16)0.0f;
    }
    __syncthreads();

    // ---- step A: conv over 18x34 domain -> dxw ----
    for (int gi = 0; gi < 10; ++gi) {
      const int G = w * 10 + gi;            // 0..39 (tail lanes read in-LDS garbage, discarded)
      const int p = G * 16 + m;
      const int r = (p * 241) >> 13;        // p/34 (exact for p < ~650)
      const int c = p - r * 34;
      const int base = (r * SWA + c) * 8;
      f32x4 acc0 = b1q0, acc1 = b1q1;
#pragma unroll
      for (int kc = 0; kc < 3; ++kc) {
        const f16x8 bfrag = *(const f16x8*)&tileA[base + off[kc]];
        acc0 = __builtin_amdgcn_mfma_f32_16x16x32_f16(af[0][kc], bfrag, acc0, 0, 0, 0);
        acc1 = __builtin_amdgcn_mfma_f32_16x16x32_f16(af[1][kc], bfrag, acc1, 0, 0, 0);
      }
      u32x4 a2d;
      {
        float g0 = gelu_fast(acc0[0]), g1 = gelu_fast(acc0[1]);
        float g2 = gelu_fast(acc0[2]), g3 = gelu_fast(acc0[3]);
        float g4 = gelu_fast(acc1[0]), g5 = gelu_fast(acc1[1]);
        float g6 = gelu_fast(acc1[2]), g7 = gelu_fast(acc1[3]);
        a2d[0] = __builtin_bit_cast(uint32_t, __builtin_amdgcn_cvt_pkrtz(g0, g1));
        a2d[1] = __builtin_bit_cast(uint32_t, __builtin_amdgcn_cvt_pkrtz(g2, g3));
        a2d[2] = __builtin_bit_cast(uint32_t, __builtin_amdgcn_cvt_pkrtz(g4, g5));
        a2d[3] = __builtin_bit_cast(uint32_t, __builtin_amdgcn_cvt_pkrtz(g6, g7));
      }
      const f16x8 a2 = __builtin_bit_cast(f16x8, a2d);
      f32x4 acc2 = {b2v, b2v, b2v, b2v};
      acc2 = __builtin_amdgcn_mfma_f32_16x16x32_f16(a2, w2fr, acc2, 0, 0, 0);
      const int pp = G * 16 + q * 4;        // quad-aligned pixel of reg 0
      if (m < 8 && pp < NA) {
        _Float16* wp = &dxw[(pp >> 2) * 40 + m];
        wp[0]  = (_Float16)acc2[0];
        wp[8]  = (_Float16)acc2[1];
        wp[16] = (_Float16)acc2[2];
        wp[24] = (_Float16)acc2[3];
      }
    }
    __syncthreads();

    // ---- assemble x_{i+1} IN PLACE (element-wise; OOB ring: xi=0, mk=0 -> 0) ----
#pragma unroll
    for (int k = 0; k < 3; ++k) {
      const int p = tid + k * 256;
      if (p < NA) {
        const int r = (p * 241) >> 13;
        const int c = p - r * 34;
        const int gy = by * TY + r - 1, gx = bx * TX + c - 1;
        _Float16 mk = (_Float16)0.0f;
        if (((unsigned)gy < HH) && ((unsigned)gx < WW)) {
          uint32_t r0, r1;
          tf2x32(k0a, k1a, 0u, (uint32_t)(gy * WW + gx), r0, r1);
          mk = (((r0 ^ r1) >> 9) > 0x400000u) ? (_Float16)0.1f : (_Float16)0.0f;
        }
        _Float16* xp = &tileA[((r + 1) * SWA + (c + 1)) * 8];
        const f16x8 xi = *(const f16x8*)xp;
        const f16x8 dx = *(const f16x8*)&dxw[(p >> 2) * 40 + (p & 3) * 8];
        const f16x8 mk8 = {mk, mk, mk, mk, mk, mk, mk, mk};
        const f16x8 xo = dx * mk8 + xi;     // v_pk_fma_f16 x4
        *(f16x8*)xp = xo;
      }
    }
    __syncthreads();

    // ---- step B: conv over 16x32 output (tileA center, offset (1,1)) -> dxw ----
    for (int gi = 0; gi < 8; ++gi) {
      const int G = w * 8 + gi;             // wave w covers output pixels 128w..128w+127
      const int p = G * 16 + m;
      const int r = p >> 5, c = p & 31;
      const int base = ((r + 1) * SWA + (c + 1)) * 8;
      f32x4 acc0 = b1q0, acc1 = b1q1;
#pragma unroll
      for (int kc = 0; kc < 3; ++kc) {
        const f16x8 bfrag = *(const f16x8*)&tileA[base + off[kc]];
        acc0 = __builtin_amdgcn_mfma_f32_16x16x32_f16(af[0][kc], bfrag, acc0, 0, 0, 0);
        acc1 = __builtin_amdgcn_mfma_f32_16x16x32_f16(af[1][kc], bfrag, acc1, 0, 0, 0);
      }
      u32x4 a2d;
      {
        float g0 = gelu_fast(acc0[0]), g1 = gelu_fast(acc0[1]);
        float g2 = gelu_fast(acc0[2]), g3 = gelu_fast(acc0[3]);
        float g4 = gelu_fast(acc1[0]), g5 = gelu_fast(acc1[1]);
        float g6 = gelu_fast(acc1[2]), g7 = gelu_fast(acc1[3]);
        a2d[0] = __builtin_bit_cast(uint32_t, __builtin_amdgcn_cvt_pkrtz(g0, g1));
        a2d[1] = __builtin_bit_cast(uint32_t, __builtin_amdgcn_cvt_pkrtz(g2, g3));
        a2d[2] = __builtin_bit_cast(uint32_t, __builtin_amdgcn_cvt_pkrtz(g4, g5));
        a2d[3] = __builtin_bit_cast(uint32_t, __builtin_amdgcn_cvt_pkrtz(g6, g7));
      }
      const f16x8 a2 = __builtin_bit_cast(f16x8, a2d);
      f32x4 acc2 = {b2v, b2v, b2v, b2v};
      acc2 = __builtin_amdgcn_mfma_f32_16x16x32_f16(a2, w2fr, acc2, 0, 0, 0);
      if (m < 8) {
        const int pp = G * 16 + q * 4;
        _Float16* wp = &dxw[(pp >> 2) * 40 + m];
        wp[0]  = (_Float16)acc2[0];
        wp[8]  = (_Float16)acc2[1];
        wp[16] = (_Float16)acc2[2];
        wp[24] = (_Float16)acc2[3];
      }
    }

    // ---- wave-local coalesced update: x_{i+2} = x_{i+1} + dx*(0.1*maskB) -> dst ----
#pragma unroll
    for (int half = 0; half < 2; ++half) {
      const int pw = half * 64 + lane;
      const int p = w * 128 + pw;
      const int py = p >> 5, px = p & 31;
      const uint32_t gp = (uint32_t)((by * TY + py) * WW + bx * TX + px);
      const _Float16 mk = maskB[half];
      const f16x8 xi = *(const f16x8*)&tileA[((py + 2) * SWA + (px + 2)) * 8];
      const f16x8 dx = *(const f16x8*)&dxw[(p >> 2) * 40 + (p & 3) * 8];
      const f16x8 mk8 = {mk, mk, mk, mk, mk, mk, mk, mk};
      const f16x8 xo = dx * mk8 + xi;       // v_pk_fma_f16 x4
      *(f16x8*)(dst + (size_t)gp * 8) = xo;
    }
  }
}

// ---- projection: out[p] = bp + sum_c x[p][c]*Wp[c] ----
__global__ void proj_kernel(const _Float16* __restrict__ x,
                            const float* __restrict__ Wp,
                            const float* __restrict__ bp,
                            float* __restrict__ out) {
  int p = blockIdx.x * blockDim.x + threadIdx.x;
  if (p >= HH * WW) return;
  const f16x8 xv = *(const f16x8*)(x + (size_t)p * 8);
  float acc = bp[0];
#pragma unroll
  for (int c = 0; c < SD; ++c) acc = fmaf((float)xv[c], Wp[c], acc);
  out[p] = acc;
}

extern "C" void kernel_launch(void* const* d_in, const int* in_sizes, int n_in,
                              void* d_out, int out_size, void* d_ws, size_t ws_size,
                              hipStream_t stream) {
  (void)in_sizes; (void)n_in; (void)out_size; (void)ws_size;
  const float* seed = (const float*)d_in[0];
  const float* W1   = (const float*)d_in[1];
  const float* b1   = (const float*)d_in[2];
  const float* W2   = (const float*)d_in[3];
  const float* b2   = (const float*)d_in[4];
  const float* Wp   = (const float*)d_in[5];
  const float* bp   = (const float*)d_in[6];
  float* out  = (float*)d_out;
  _Float16* buf0 = (_Float16*)d_ws;
  _Float16* buf1 = buf0 + (size_t)SD * HH * WW;
  _Float16* w1f  = buf1 + (size_t)SD * HH * WW;
  _Float16* w2f  = w1f + 2 * 3 * 64 * 8;

  // 64 subkeys of jax.random.split(jax.random.key(42), 64) (raw pairs, no xor)
  uint32_t ka[64], kb[64];
  for (int i = 0; i < 64; ++i) tf2x32(0u, 42u, 0u, (uint32_t)i, ka[i], kb[i]);

  hipLaunchKernelGGL(prep_kernel, dim3(1), dim3(256), 0, stream, W1, W2, w1f, w2f);
  hipLaunchKernelGGL(init_kernel, dim3((HH * WW) / 256), dim3(256), 0, stream, seed, buf0);

  dim3 grid(WW / TX, 32);  // each block: tile rows by and by+32 (tail-free schedule)
  _Float16* s = buf0; _Float16* d = buf1;
  for (int i = 0; i < 64; i += 2) {
    hipLaunchKernelGGL(step2_kernel, grid, dim3(256), 0, stream,
                       s, d, w1f, w2f, b1, b2, ka[i], kb[i], ka[i + 1], kb[i + 1]);
    _Float16* t = s; s = d; d = t;
  }
  hipLaunchKernelGGL(proj_kernel, dim3((HH * WW) / 256), dim3(256), 0, stream,
                     s, Wp, bp, out);
}

// Round 12
// 1388.529 us; speedup vs baseline: 1.3659x; 1.0442x over previous
//
#include <hip/hip_runtime.h>
#include <cstdint>
#include <cstddef>

// NCA, 2 steps fused per launch; each block processes TWO tiles (tail-free: 1024 blocks
// x 2 tiles, 4 blocks/CU full-duration). State: NHWC f16, double-buffered in d_ws.
// Per tile (output 16x32): stage 20x36 halo-2 tileA -> step A conv over 18x34 domain
// (ring recomputed bit-identically by neighbors; no seams) -> assemble x_{i+1} in place
// -> step B conv over 16x32 -> masked update -> dst.
// Convs via mfma_f32_16x16x32_f16:
//   conv3x3: mfma(A=W1frag, B=pixels). W1 rows PERMUTED (row i -> hidden ch
//   (i>>2)*8+(i&3), +4 for the second 16) so lane (q,m) ends up holding hidden chs
//   q*8+{0..7} of pixel m after the acc0/acc1 pkrtz pack = natural-k B-operand.
//   conv1x1: mfma(A=W2frag identity-k, B=h) -> lane (q<2,m) holds out-chs q*4+{0..3}
//   of pixel m -> ONE ds_write_b64 to pixel-major dxw (2-way bank alias = free).
// Updates in packed f16 (v_pk_fma_f16): x' = dx*(0.1*mask) + x.
// gelu: tanh form x - x/(1+e^{2w}), 2w = x*(1.5957691+0.0713548 x^2), |err|~1.5e-4.
// PRNG: jax threefry2x32 partitionable: subkey[i]=raw pair tf2x32((0,42),(0,i));
// bits[p]=o0^o1 of tf2x32(subkey,(0,p)); mask = (bits>>9) > 2^22.

#define HH 1024
#define WW 1024
#define SD 8
#define TX 32
#define TY 16
#define NA 612           // step-A domain: 18*34
#define SWA 36           // tileA row stride (pixels)

typedef _Float16 f16x8 __attribute__((ext_vector_type(8)));
typedef float f32x4 __attribute__((ext_vector_type(4)));
typedef uint32_t u32x2 __attribute__((ext_vector_type(2)));
typedef uint32_t u32x4 __attribute__((ext_vector_type(4)));

__host__ __device__ inline uint32_t rotl32(uint32_t x, int n) {
  return (x << n) | (x >> (32 - n));
}

__host__ __device__ inline void tf2x32(uint32_t k0, uint32_t k1,
                                       uint32_t x0, uint32_t x1,
                                       uint32_t& o0, uint32_t& o1) {
  uint32_t ks0 = k0, ks1 = k1, ks2 = k0 ^ k1 ^ 0x1BD11BDAu;
  x0 += ks0; x1 += ks1;
#define TFR(r) { x0 += x1; x1 = rotl32(x1, (r)); x1 ^= x0; }
  TFR(13) TFR(15) TFR(26) TFR(6)  x0 += ks1; x1 += ks2 + 1u;
  TFR(17) TFR(29) TFR(16) TFR(24) x0 += ks2; x1 += ks0 + 2u;
  TFR(13) TFR(15) TFR(26) TFR(6)  x0 += ks0; x1 += ks1 + 3u;
  TFR(17) TFR(29) TFR(16) TFR(24) x0 += ks1; x1 += ks2 + 4u;
  TFR(13) TFR(15) TFR(26) TFR(6)  x0 += ks2; x1 += ks0 + 5u;
#undef TFR
  o0 = x0; o1 = x1;
}

// gelu tanh-form: x - x/(1+e^{2w}), 2w = x*(1.5957691 + 0.0713548*x^2).
__device__ inline float gelu_fast(float x) {
  const float s = x * x;
  const float z = x * fmaf(0.0713548162f, s, 1.5957691216f);
  const float e = __expf(z);
  const float t = __builtin_amdgcn_rcpf(1.0f + e);
  return fmaf(-x, t, x);
}

// ---- bilinear upsample 8x8 -> 1024x1024, NHWC f16 out ----
__global__ void init_kernel(const float* __restrict__ seed, _Float16* __restrict__ dst) {
  int p = blockIdx.x * blockDim.x + threadIdx.x;
  if (p >= HH * WW) return;
  int y = p >> 10, x = p & 1023;
  float fy = (y + 0.5f) * (8.0f / HH) - 0.5f;
  float fx = (x + 0.5f) * (8.0f / WW) - 0.5f;
  int y0 = (int)floorf(fy); float wy = fy - (float)y0;
  int x0 = (int)floorf(fx); float wx = fx - (float)x0;
  int y0c = min(max(y0, 0), 7), y1c = min(max(y0 + 1, 0), 7);
  int x0c = min(max(x0, 0), 7), x1c = min(max(x0 + 1, 0), 7);
  f16x8 v;
#pragma unroll
  for (int c = 0; c < SD; ++c) {
    const float* s = seed + c * 64;
    float v00 = s[y0c * 8 + x0c], v01 = s[y0c * 8 + x1c];
    float v10 = s[y1c * 8 + x0c], v11 = s[y1c * 8 + x1c];
    float v0 = v00 + (v01 - v00) * wx;
    float v1 = v10 + (v11 - v10) * wx;
    v[c] = (_Float16)(v0 + (v1 - v0) * wy);
  }
  *(f16x8*)(dst + (size_t)p * 8) = v;
}

// ---- pack W1 (A-frags, PERMUTED rows) and W2 (A-frag, identity k-order) ----
// W1f: frag row i = lane&15 -> hidden ch (i>>2)*8+(i&3) (nt=0) / +4 (nt=1);
//      k = kc*32+(lane>>4)*8+j = tap*8+c -> tap = kc*4+(lane>>4), c = j.
// W2f: row n = lane&15 (out-ch, <8 valid), k = (lane>>4)*8+j = hidden ch directly.
__global__ void prep_kernel(const float* __restrict__ W1, const float* __restrict__ W2,
                            _Float16* __restrict__ w1f, _Float16* __restrict__ w2f) {
  int tid = threadIdx.x;
  for (int i = tid; i < 2 * 3 * 64; i += 256) {
    int nt = i / 192, rem = i % 192;
    int kc = rem / 64, lane = rem % 64;
    int ir = lane & 15;
    int ch = (ir >> 2) * 8 + (ir & 3) + nt * 4;   // permuted hidden channel
    int tap = kc * 4 + (lane >> 4);
#pragma unroll
    for (int j = 0; j < 8; ++j) {
      float v = (tap < 9) ? W1[(ch * SD + j) * 9 + tap] : 0.0f;
      w1f[i * 8 + j] = (_Float16)v;
    }
  }
  if (tid < 64) {
    int n = tid & 15, qk = tid >> 4;
#pragma unroll
    for (int j = 0; j < 8; ++j) {
      float v = (n < 8) ? W2[n * 32 + qk * 8 + j] : 0.0f;
      w2f[tid * 8 + j] = (_Float16)v;
    }
  }
}

// ---- fused double NCA step, 2 tiles per block ----
__global__ __launch_bounds__(256) void step2_kernel(
    const _Float16* __restrict__ src, _Float16* __restrict__ dst,
    const _Float16* __restrict__ w1f, const _Float16* __restrict__ w2f,
    const float* __restrict__ b1, const float* __restrict__ b2,
    uint32_t k0a, uint32_t k1a, uint32_t k0b, uint32_t k1b) {
  __shared__ _Float16 tileA[20 * SWA * SD];   // 11520 B
  __shared__ _Float16 dxw[NA * SD];           // 9792 B, pixel-major [px][ch]

  const int tid = threadIdx.x;
  const int bx = blockIdx.x;
  const int lane = tid & 63, w = tid >> 6;
  const int m = lane & 15, q = lane >> 4;

  // ---- weight fragments + biases ----
  f16x8 af[2][3];
#pragma unroll
  for (int nt = 0; nt < 2; ++nt)
#pragma unroll
    for (int kc = 0; kc < 3; ++kc)
      af[nt][kc] = *(const f16x8*)(w1f + ((nt * 3 + kc) * 64 + lane) * 8);
  const f16x8 w2fr = *(const f16x8*)(w2f + lane * 8);
  // acc0 rows = hidden ch q*8+r, acc1 rows = q*8+4+r (W1 permutation)
  const f32x4 b1q0 = *(const f32x4*)(b1 + q * 8);
  const f32x4 b1q1 = *(const f32x4*)(b1 + q * 8 + 4);
  // conv1x1 D rows = out-ch q*4+r (q<2 valid)
  const f32x4 b2q = *(const f32x4*)(b2 + (q & 1) * 4);

  // per-lane tap offsets (taps 9..11 are zero-weight rows; clamp addr)
  int off[3];
#pragma unroll
  for (int kc = 0; kc < 3; ++kc) {
    int t = kc * 4 + q; if (t > 8) t = 0;
    off[kc] = ((t / 3) * SWA + (t % 3)) * 8;
  }

#pragma unroll 1
  for (int it2 = 0; it2 < 2; ++it2) {
    const int by = blockIdx.y + it2 * 32;   // tile rows: by and by+32
    if (it2) __syncthreads();               // protect tileA/dxw reuse across tiles

    // ---- stage halo-2 f16 tile (zero outside) ----
    for (int i = tid; i < 20 * SWA; i += 256) {
      int ly = i / SWA, lx = i - (i / SWA) * SWA;
      int gy = by * TY + ly - 2, gx = bx * TX + lx - 2;
      u32x4 v = {0u, 0u, 0u, 0u};
      if ((unsigned)gy < HH && (unsigned)gx < WW)
        v = *(const u32x4*)(src + (size_t)(gy * WW + gx) * 8);
      *(u32x4*)&tileA[i * 8] = v;
    }

    // ---- step-B masks for this thread's 2 update pixels (wave-local) ----
    _Float16 maskB[2];
#pragma unroll
    for (int half = 0; half < 2; ++half) {
      const int p = w * 128 + half * 64 + lane;
      const uint32_t gp = (uint32_t)((by * TY + (p >> 5)) * WW + bx * TX + (p & 31));
      uint32_t r0, r1;
      tf2x32(k0b, k1b, 0u, gp, r0, r1);
      maskB[half] = (((r0 ^ r1) >> 9) > 0x400000u) ? (_Float16)0.1f : (_Float16)0.0f;
    }
    __syncthreads();

    // ---- step A: conv over 18x34 domain -> dxw ----
    for (int gi = 0; gi < 10; ++gi) {
      const int G = w * 10 + gi;            // 0..39 (tail lanes discarded by guard)
      const int p = G * 16 + m;
      const int r = (p * 241) >> 13;        // p/34 (exact for p < ~650)
      const int c = p - r * 34;
      const int base = (r * SWA + c) * 8;
      f32x4 acc0 = b1q0, acc1 = b1q1;
#pragma unroll
      for (int kc = 0; kc < 3; ++kc) {
        const f16x8 bfrag = *(const f16x8*)&tileA[base + off[kc]];
        acc0 = __builtin_amdgcn_mfma_f32_16x16x32_f16(af[0][kc], bfrag, acc0, 0, 0, 0);
        acc1 = __builtin_amdgcn_mfma_f32_16x16x32_f16(af[1][kc], bfrag, acc1, 0, 0, 0);
      }
      // lane (q,m) holds hidden chs q*8+{0..3} (acc0), q*8+{4..7} (acc1) of pixel p.
      u32x4 a2d;
      {
        float g0 = gelu_fast(acc0[0]), g1 = gelu_fast(acc0[1]);
        float g2 = gelu_fast(acc0[2]), g3 = gelu_fast(acc0[3]);
        float g4 = gelu_fast(acc1[0]), g5 = gelu_fast(acc1[1]);
        float g6 = gelu_fast(acc1[2]), g7 = gelu_fast(acc1[3]);
        a2d[0] = __builtin_bit_cast(uint32_t, __builtin_amdgcn_cvt_pkrtz(g0, g1));
        a2d[1] = __builtin_bit_cast(uint32_t, __builtin_amdgcn_cvt_pkrtz(g2, g3));
        a2d[2] = __builtin_bit_cast(uint32_t, __builtin_amdgcn_cvt_pkrtz(g4, g5));
        a2d[3] = __builtin_bit_cast(uint32_t, __builtin_amdgcn_cvt_pkrtz(g6, g7));
      }
      const f16x8 hB = __builtin_bit_cast(f16x8, a2d);   // B-operand, k = ch
      f32x4 acc2 = b2q;
      acc2 = __builtin_amdgcn_mfma_f32_16x16x32_f16(w2fr, hB, acc2, 0, 0, 0);
      // lane (q<2,m): out-chs q*4+{0..3} of pixel p -> one b64 pixel-major write
      if (q < 2 && p < NA) {
        u32x2 dd;
        dd[0] = __builtin_bit_cast(uint32_t, __builtin_amdgcn_cvt_pkrtz(acc2[0], acc2[1]));
        dd[1] = __builtin_bit_cast(uint32_t, __builtin_amdgcn_cvt_pkrtz(acc2[2], acc2[3]));
        *(u32x2*)&dxw[p * 8 + q * 4] = dd;
      }
    }
    __syncthreads();

    // ---- assemble x_{i+1} IN PLACE (element-wise; OOB ring: xi=0, mk=0 -> 0) ----
#pragma unroll
    for (int k = 0; k < 3; ++k) {
      const int p = tid + k * 256;
      if (p < NA) {
        const int r = (p * 241) >> 13;
        const int c = p - r * 34;
        const int gy = by * TY + r - 1, gx = bx * TX + c - 1;
        _Float16 mk = (_Float16)0.0f;
        if (((unsigned)gy < HH) && ((unsigned)gx < WW)) {
          uint32_t r0, r1;
          tf2x32(k0a, k1a, 0u, (uint32_t)(gy * WW + gx), r0, r1);
          mk = (((r0 ^ r1) >> 9) > 0x400000u) ? (_Float16)0.1f : (_Float16)0.0f;
        }
        _Float16* xp = &tileA[((r + 1) * SWA + (c + 1)) * 8];
        const f16x8 xi = *(const f16x8*)xp;
        const f16x8 dx = *(const f16x8*)&dxw[p * 8];
        const f16x8 mk8 = {mk, mk, mk, mk, mk, mk, mk, mk};
        const f16x8 xo = dx * mk8 + xi;     // v_pk_fma_f16 x4
        *(f16x8*)xp = xo;
      }
    }
    __syncthreads();

    // ---- step B: conv over 16x32 output (tileA center, offset (1,1)) -> dxw ----
    for (int gi = 0; gi < 8; ++gi) {
      const int G = w * 8 + gi;             // wave w covers output pixels 128w..128w+127
      const int p = G * 16 + m;
      const int r = p >> 5, c = p & 31;
      const int base = ((r + 1) * SWA + (c + 1)) * 8;
      f32x4 acc0 = b1q0, acc1 = b1q1;
#pragma unroll
      for (int kc = 0; kc < 3; ++kc) {
        const f16x8 bfrag = *(const f16x8*)&tileA[base + off[kc]];
        acc0 = __builtin_amdgcn_mfma_f32_16x16x32_f16(af[0][kc], bfrag, acc0, 0, 0, 0);
        acc1 = __builtin_amdgcn_mfma_f32_16x16x32_f16(af[1][kc], bfrag, acc1, 0, 0, 0);
      }
      u32x4 a2d;
      {
        float g0 = gelu_fast(acc0[0]), g1 = gelu_fast(acc0[1]);
        float g2 = gelu_fast(acc0[2]), g3 = gelu_fast(acc0[3]);
        float g4 = gelu_fast(acc1[0]), g5 = gelu_fast(acc1[1]);
        float g6 = gelu_fast(acc1[2]), g7 = gelu_fast(acc1[3]);
        a2d[0] = __builtin_bit_cast(uint32_t, __builtin_amdgcn_cvt_pkrtz(g0, g1));
        a2d[1] = __builtin_bit_cast(uint32_t, __builtin_amdgcn_cvt_pkrtz(g2, g3));
        a2d[2] = __builtin_bit_cast(uint32_t, __builtin_amdgcn_cvt_pkrtz(g4, g5));
        a2d[3] = __builtin_bit_cast(uint32_t, __builtin_amdgcn_cvt_pkrtz(g6, g7));
      }
      const f16x8 hB = __builtin_bit_cast(f16x8, a2d);
      f32x4 acc2 = b2q;
      acc2 = __builtin_amdgcn_mfma_f32_16x16x32_f16(w2fr, hB, acc2, 0, 0, 0);
      if (q < 2) {
        u32x2 dd;
        dd[0] = __builtin_bit_cast(uint32_t, __builtin_amdgcn_cvt_pkrtz(acc2[0], acc2[1]));
        dd[1] = __builtin_bit_cast(uint32_t, __builtin_amdgcn_cvt_pkrtz(acc2[2], acc2[3]));
        *(u32x2*)&dxw[p * 8 + q * 4] = dd;
      }
    }

    // ---- wave-local coalesced update: x_{i+2} = x_{i+1} + dx*(0.1*maskB) -> dst ----
#pragma unroll
    for (int half = 0; half < 2; ++half) {
      const int pw = half * 64 + lane;
      const int p = w * 128 + pw;
      const int py = p >> 5, px = p & 31;
      const uint32_t gp = (uint32_t)((by * TY + py) * WW + bx * TX + px);
      const _Float16 mk = maskB[half];
      const f16x8 xi = *(const f16x8*)&tileA[((py + 2) * SWA + (px + 2)) * 8];
      const f16x8 dx = *(const f16x8*)&dxw[p * 8];
      const f16x8 mk8 = {mk, mk, mk, mk, mk, mk, mk, mk};
      const f16x8 xo = dx * mk8 + xi;       // v_pk_fma_f16 x4
      *(f16x8*)(dst + (size_t)gp * 8) = xo;
    }
  }
}

// ---- projection: out[p] = bp + sum_c x[p][c]*Wp[c] ----
__global__ void proj_kernel(const _Float16* __restrict__ x,
                            const float* __restrict__ Wp,
                            const float* __restrict__ bp,
                            float* __restrict__ out) {
  int p = blockIdx.x * blockDim.x + threadIdx.x;
  if (p >= HH * WW) return;
  const f16x8 xv = *(const f16x8*)(x + (size_t)p * 8);
  float acc = bp[0];
#pragma unroll
  for (int c = 0; c < SD; ++c) acc = fmaf((float)xv[c], Wp[c], acc);
  out[p] = acc;
}

extern "C" void kernel_launch(void* const* d_in, const int* in_sizes, int n_in,
                              void* d_out, int out_size, void* d_ws, size_t ws_size,
                              hipStream_t stream) {
  (void)in_sizes; (void)n_in; (void)out_size; (void)ws_size;
  const float* seed = (const float*)d_in[0];
  const float* W1   = (const float*)d_in[1];
  const float* b1   = (const float*)d_in[2];
  const float* W2   = (const float*)d_in[3];
  const float* b2   = (const float*)d_in[4];
  const float* Wp   = (const float*)d_in[5];
  const float* bp   = (const float*)d_in[6];
  float* out  = (float*)d_out;
  _Float16* buf0 = (_Float16*)d_ws;
  _Float16* buf1 = buf0 + (size_t)SD * HH * WW;
  _Float16* w1f  = buf1 + (size_t)SD * HH * WW;
  _Float16* w2f  = w1f + 2 * 3 * 64 * 8;

  // 64 subkeys of jax.random.split(jax.random.key(42), 64) (raw pairs, no xor)
  uint32_t ka[64], kb[64];
  for (int i = 0; i < 64; ++i) tf2x32(0u, 42u, 0u, (uint32_t)i, ka[i], kb[i]);

  hipLaunchKernelGGL(prep_kernel, dim3(1), dim3(256), 0, stream, W1, W2, w1f, w2f);
  hipLaunchKernelGGL(init_kernel, dim3((HH * WW) / 256), dim3(256), 0, stream, seed, buf0);

  dim3 grid(WW / TX, 32);  // each block: tile rows by and by+32 (tail-free schedule)
  _Float16* s = buf0; _Float16* d = buf1;
  for (int i = 0; i < 64; i += 2) {
    hipLaunchKernelGGL(step2_kernel, grid, dim3(256), 0, stream,
                       s, d, w1f, w2f, b1, b2, ka[i], kb[i], ka[i + 1], kb[i + 1]);
    _Float16* t = s; s = d; d = t;
  }
  hipLaunchKernelGGL(proj_kernel, dim3((HH * WW) / 256), dim3(256), 0, stream,
                     s, Wp, bp, out);
}

// Round 13
// 1336.339 us; speedup vs baseline: 1.4192x; 1.0391x over previous
//
#include <hip/hip_runtime.h>
#include <cstdint>
#include <cstddef>

// NCA, 2 steps fused per launch. 32x32 output tile, 512 threads, 1 tile-pair/block,
// grid 32x32 = 1024 blocks = exactly 4/CU. State: NHWC f16, double-buffered in d_ws.
// TWO barriers per block:
//   stage 36x36 halo-2 tileA -> B1
//   conv A over 34x34 domain -> dxw(dx) ; wave-local assemble: dxw <- x_{i+1}
//     (reads own dxw + tileA centers; tileA not modified; intra-wave ds order)
//   B2
//   conv B over 32x32 (reads dxw as state, 34-wide) -> dx into tileA-as-scratch ;
//   wave-local update: dst = tileA_scratch*0.1mask + dxw   (dxw frozen since B2)
// Ring pixels recomputed bit-identically by neighbor blocks -> no seams.
// Convs via mfma_f32_16x16x32_f16: A=W1 (rows permuted so lane(q,m) holds hidden chs
// q*8+{0..7} of pixel m after pkrtz pack = natural-k B-operand), then
// mfma(A=W2 identity-k, B=h) -> lane(q<2,m) = out-chs q*4+{0..3} of pixel m -> b64 write.
// gelu: tanh form x - x/(1+e^{2w}), 2w = x*(1.5957691+0.0713548 x^2), |err|~1.5e-4.
// PRNG: jax threefry2x32 partitionable: subkey[i]=raw pair tf2x32((0,42),(0,i));
// bits[p]=o0^o1 of tf2x32(subkey,(0,p)); mask = (bits>>9) > 2^22.

#define HH 1024
#define WW 1024
#define SD 8
#define TX 32
#define TY 32
#define DA 34            // domain-A width/height (34x34)
#define NA 1156          // 34*34
#define NGA 73           // ceil(1156/16)
#define SWA 36           // tileA row stride (pixels)

typedef _Float16 f16x8 __attribute__((ext_vector_type(8)));
typedef float f32x4 __attribute__((ext_vector_type(4)));
typedef uint32_t u32x2 __attribute__((ext_vector_type(2)));
typedef uint32_t u32x4 __attribute__((ext_vector_type(4)));

__host__ __device__ inline uint32_t rotl32(uint32_t x, int n) {
  return (x << n) | (x >> (32 - n));
}

__host__ __device__ inline void tf2x32(uint32_t k0, uint32_t k1,
                                       uint32_t x0, uint32_t x1,
                                       uint32_t& o0, uint32_t& o1) {
  uint32_t ks0 = k0, ks1 = k1, ks2 = k0 ^ k1 ^ 0x1BD11BDAu;
  x0 += ks0; x1 += ks1;
#define TFR(r) { x0 += x1; x1 = rotl32(x1, (r)); x1 ^= x0; }
  TFR(13) TFR(15) TFR(26) TFR(6)  x0 += ks1; x1 += ks2 + 1u;
  TFR(17) TFR(29) TFR(16) TFR(24) x0 += ks2; x1 += ks0 + 2u;
  TFR(13) TFR(15) TFR(26) TFR(6)  x0 += ks0; x1 += ks1 + 3u;
  TFR(17) TFR(29) TFR(16) TFR(24) x0 += ks1; x1 += ks2 + 4u;
  TFR(13) TFR(15) TFR(26) TFR(6)  x0 += ks2; x1 += ks0 + 5u;
#undef TFR
  o0 = x0; o1 = x1;
}

// gelu tanh-form: x - x/(1+e^{2w}), 2w = x*(1.5957691 + 0.0713548*x^2).
__device__ inline float gelu_fast(float x) {
  const float s = x * x;
  const float z = x * fmaf(0.0713548162f, s, 1.5957691216f);
  const float e = __expf(z);
  const float t = __builtin_amdgcn_rcpf(1.0f + e);
  return fmaf(-x, t, x);
}

// ---- bilinear upsample 8x8 -> 1024x1024, NHWC f16 out ----
__global__ void init_kernel(const float* __restrict__ seed, _Float16* __restrict__ dst) {
  int p = blockIdx.x * blockDim.x + threadIdx.x;
  if (p >= HH * WW) return;
  int y = p >> 10, x = p & 1023;
  float fy = (y + 0.5f) * (8.0f / HH) - 0.5f;
  float fx = (x + 0.5f) * (8.0f / WW) - 0.5f;
  int y0 = (int)floorf(fy); float wy = fy - (float)y0;
  int x0 = (int)floorf(fx); float wx = fx - (float)x0;
  int y0c = min(max(y0, 0), 7), y1c = min(max(y0 + 1, 0), 7);
  int x0c = min(max(x0, 0), 7), x1c = min(max(x0 + 1, 0), 7);
  f16x8 v;
#pragma unroll
  for (int c = 0; c < SD; ++c) {
    const float* s = seed + c * 64;
    float v00 = s[y0c * 8 + x0c], v01 = s[y0c * 8 + x1c];
    float v10 = s[y1c * 8 + x0c], v11 = s[y1c * 8 + x1c];
    float v0 = v00 + (v01 - v00) * wx;
    float v1 = v10 + (v11 - v10) * wx;
    v[c] = (_Float16)(v0 + (v1 - v0) * wy);
  }
  *(f16x8*)(dst + (size_t)p * 8) = v;
}

// ---- pack W1 (A-frags, PERMUTED rows) and W2 (A-frag, identity k-order) ----
__global__ void prep_kernel(const float* __restrict__ W1, const float* __restrict__ W2,
                            _Float16* __restrict__ w1f, _Float16* __restrict__ w2f) {
  int tid = threadIdx.x;
  for (int i = tid; i < 2 * 3 * 64; i += 256) {
    int nt = i / 192, rem = i % 192;
    int kc = rem / 64, lane = rem % 64;
    int ir = lane & 15;
    int ch = (ir >> 2) * 8 + (ir & 3) + nt * 4;   // permuted hidden channel
    int tap = kc * 4 + (lane >> 4);
#pragma unroll
    for (int j = 0; j < 8; ++j) {
      float v = (tap < 9) ? W1[(ch * SD + j) * 9 + tap] : 0.0f;
      w1f[i * 8 + j] = (_Float16)v;
    }
  }
  if (tid < 64) {
    int n = tid & 15, qk = tid >> 4;
#pragma unroll
    for (int j = 0; j < 8; ++j) {
      float v = (n < 8) ? W2[n * 32 + qk * 8 + j] : 0.0f;
      w2f[tid * 8 + j] = (_Float16)v;
    }
  }
}

// ---- fused double NCA step, 32x32 tile, 512 threads, 2 barriers ----
__global__ __launch_bounds__(512, 8) void step2_kernel(
    const _Float16* __restrict__ src, _Float16* __restrict__ dst,
    const _Float16* __restrict__ w1f, const _Float16* __restrict__ w2f,
    const float* __restrict__ b1, const float* __restrict__ b2,
    uint32_t k0a, uint32_t k1a, uint32_t k0b, uint32_t k1b) {
  __shared__ _Float16 tileA[SWA * SWA * SD];  // 20736 B (state; later conv-B dx scratch)
  __shared__ _Float16 dxw[NA * SD];           // 18496 B (conv-A dx -> x_{i+1})

  const int tid = threadIdx.x;
  const int bx = blockIdx.x, by = blockIdx.y;
  const int lane = tid & 63, w = tid >> 6;    // 8 waves
  const int m = lane & 15, q = lane >> 4;

  // ---- weight fragments + biases ----
  f16x8 af[2][3];
#pragma unroll
  for (int nt = 0; nt < 2; ++nt)
#pragma unroll
    for (int kc = 0; kc < 3; ++kc)
      af[nt][kc] = *(const f16x8*)(w1f + ((nt * 3 + kc) * 64 + lane) * 8);
  const f16x8 w2fr = *(const f16x8*)(w2f + lane * 8);
  const f32x4 b1q0 = *(const f32x4*)(b1 + q * 8);        // hidden chs q*8+{0..3}
  const f32x4 b1q1 = *(const f32x4*)(b1 + q * 8 + 4);    // hidden chs q*8+{4..7}
  const f32x4 b2q = *(const f32x4*)(b2 + (q & 1) * 4);   // out-chs q*4+{0..3} (q<2)

  // per-lane tap offsets for tileA (stride 36) and dxw-as-state (stride 34)
  int offA[3], offB[3];
#pragma unroll
  for (int kc = 0; kc < 3; ++kc) {
    int t = kc * 4 + q; if (t > 8) t = 0;     // taps 9..11: zero-weight rows, clamp addr
    offA[kc] = ((t / 3) * SWA + (t % 3)) * 8;
    offB[kc] = ((t / 3) * DA + (t % 3)) * 8;
  }

  // ---- stage halo-2 f16 tile: rows by*32-2.., cols bx*32-2.. (zero outside) ----
  for (int i = tid; i < SWA * SWA; i += 512) {
    int ly = i / SWA, lx = i - (i / SWA) * SWA;
    int gy = by * TY + ly - 2, gx = bx * TX + lx - 2;
    u32x4 v = {0u, 0u, 0u, 0u};
    if ((unsigned)gy < HH && (unsigned)gx < WW)
      v = *(const u32x4*)(src + (size_t)(gy * WW + gx) * 8);
    *(u32x4*)&tileA[i * 8] = v;
  }
  __syncthreads();                            // B1

  // ---- conv A over 34x34 domain -> dxw (dx), strided groups G = w + 8*gi ----
  for (int gi = 0; gi < 10; ++gi) {
    const int G = w + 8 * gi;                 // wave-uniform
    if (G >= NGA) break;
    const int p = G * 16 + m;                 // domain-A pixel (G=72: lanes m>=4 garbage,
    const int r = (p * 241) >> 13;            //  guarded below; OOB reads land in dxw, safe)
    const int c = p - r * DA;
    const int base = (r * SWA + c) * 8;
    f32x4 acc0 = b1q0, acc1 = b1q1;
#pragma unroll
    for (int kc = 0; kc < 3; ++kc) {
      const f16x8 bfrag = *(const f16x8*)&tileA[base + offA[kc]];
      acc0 = __builtin_amdgcn_mfma_f32_16x16x32_f16(af[0][kc], bfrag, acc0, 0, 0, 0);
      acc1 = __builtin_amdgcn_mfma_f32_16x16x32_f16(af[1][kc], bfrag, acc1, 0, 0, 0);
    }
    u32x4 a2d;
    {
      float g0 = gelu_fast(acc0[0]), g1 = gelu_fast(acc0[1]);
      float g2 = gelu_fast(acc0[2]), g3 = gelu_fast(acc0[3]);
      float g4 = gelu_fast(acc1[0]), g5 = gelu_fast(acc1[1]);
      float g6 = gelu_fast(acc1[2]), g7 = gelu_fast(acc1[3]);
      a2d[0] = __builtin_bit_cast(uint32_t, __builtin_amdgcn_cvt_pkrtz(g0, g1));
      a2d[1] = __builtin_bit_cast(uint32_t, __builtin_amdgcn_cvt_pkrtz(g2, g3));
      a2d[2] = __builtin_bit_cast(uint32_t, __builtin_amdgcn_cvt_pkrtz(g4, g5));
      a2d[3] = __builtin_bit_cast(uint32_t, __builtin_amdgcn_cvt_pkrtz(g6, g7));
    }
    const f16x8 hB = __builtin_bit_cast(f16x8, a2d);
    f32x4 acc2 = b2q;
    acc2 = __builtin_amdgcn_mfma_f32_16x16x32_f16(w2fr, hB, acc2, 0, 0, 0);
    if (q < 2 && p < NA) {
      u32x2 dd;
      dd[0] = __builtin_bit_cast(uint32_t, __builtin_amdgcn_cvt_pkrtz(acc2[0], acc2[1]));
      dd[1] = __builtin_bit_cast(uint32_t, __builtin_amdgcn_cvt_pkrtz(acc2[2], acc2[3]));
      *(u32x2*)&dxw[p * 8 + q * 4] = dd;
    }
  }

  // ---- wave-local assemble: dxw <- x_{i+1} = tileA(center) + dx*(0.1*maskA) ----
  // (transforms only this wave's own groups; tileA untouched; intra-wave ds order)
#pragma unroll
  for (int j = 0; j < 3; ++j) {
    const int G = w + 8 * (j * 4 + (lane >> 4));   // own groups, 4 per iter
    const int p = G * 16 + m;
    if (G < NGA && p < NA) {
      const int r = (p * 241) >> 13;
      const int c = p - r * DA;
      const int gy = by * TY + r - 1, gx = bx * TX + c - 1;
      _Float16 mk = (_Float16)0.0f;
      if (((unsigned)gy < HH) && ((unsigned)gx < WW)) {
        uint32_t r0, r1;
        tf2x32(k0a, k1a, 0u, (uint32_t)(gy * WW + gx), r0, r1);
        mk = (((r0 ^ r1) >> 9) > 0x400000u) ? (_Float16)0.1f : (_Float16)0.0f;
      }
      const f16x8 xi = *(const f16x8*)&tileA[((r + 1) * SWA + (c + 1)) * 8];
      const f16x8 dx = *(const f16x8*)&dxw[p * 8];
      const f16x8 mk8 = {mk, mk, mk, mk, mk, mk, mk, mk};
      const f16x8 xo = dx * mk8 + xi;              // v_pk_fma_f16 x4 (OOB ring: 0+0=0)
      *(f16x8*)&dxw[p * 8] = xo;
    }
  }
  __syncthreads();                            // B2

  // ---- conv B over 32x32 output (state = dxw, stride 34) -> dx into tileA scratch ----
  for (int gi = 0; gi < 8; ++gi) {
    const int G = w + 8 * gi;                 // 64 groups, 8 per wave
    const int p = G * 16 + m;                 // output pixel 0..1023
    const int r = p >> 5, c = p & 31;
    const int base = (r * DA + c) * 8;
    f32x4 acc0 = b1q0, acc1 = b1q1;
#pragma unroll
    for (int kc = 0; kc < 3; ++kc) {
      const f16x8 bfrag = *(const f16x8*)&dxw[base + offB[kc]];
      acc0 = __builtin_amdgcn_mfma_f32_16x16x32_f16(af[0][kc], bfrag, acc0, 0, 0, 0);
      acc1 = __builtin_amdgcn_mfma_f32_16x16x32_f16(af[1][kc], bfrag, acc1, 0, 0, 0);
    }
    u32x4 a2d;
    {
      float g0 = gelu_fast(acc0[0]), g1 = gelu_fast(acc0[1]);
      float g2 = gelu_fast(acc0[2]), g3 = gelu_fast(acc0[3]);
      float g4 = gelu_fast(acc1[0]), g5 = gelu_fast(acc1[1]);
      float g6 = gelu_fast(acc1[2]), g7 = gelu_fast(acc1[3]);
      a2d[0] = __builtin_bit_cast(uint32_t, __builtin_amdgcn_cvt_pkrtz(g0, g1));
      a2d[1] = __builtin_bit_cast(uint32_t, __builtin_amdgcn_cvt_pkrtz(g2, g3));
      a2d[2] = __builtin_bit_cast(uint32_t, __builtin_amdgcn_cvt_pkrtz(g4, g5));
      a2d[3] = __builtin_bit_cast(uint32_t, __builtin_amdgcn_cvt_pkrtz(g6, g7));
    }
    const f16x8 hB = __builtin_bit_cast(f16x8, a2d);
    f32x4 acc2 = b2q;
    acc2 = __builtin_amdgcn_mfma_f32_16x16x32_f16(w2fr, hB, acc2, 0, 0, 0);
    if (q < 2) {
      u32x2 dd;
      dd[0] = __builtin_bit_cast(uint32_t, __builtin_amdgcn_cvt_pkrtz(acc2[0], acc2[1]));
      dd[1] = __builtin_bit_cast(uint32_t, __builtin_amdgcn_cvt_pkrtz(acc2[2], acc2[3]));
      *(u32x2*)&tileA[p * 8 + q * 4] = dd;    // tileA dead -> dx scratch
    }
  }

  // ---- wave-local update: dst = x_{i+1}(dxw, frozen since B2) + dx*(0.1*maskB) ----
#pragma unroll
  for (int j = 0; j < 2; ++j) {
    const int G = w + 8 * (j * 4 + (lane >> 4));   // own groups, 4 per iter (all < 64)
    const int p = G * 16 + m;
    const int r = p >> 5, c = p & 31;
    const int pA = (r + 1) * DA + (c + 1);
    const uint32_t gp = (uint32_t)((by * TY + r) * WW + bx * TX + c);
    uint32_t r0, r1;
    tf2x32(k0b, k1b, 0u, gp, r0, r1);
    const _Float16 mk = (((r0 ^ r1) >> 9) > 0x400000u) ? (_Float16)0.1f : (_Float16)0.0f;
    const f16x8 xB = *(const f16x8*)&dxw[pA * 8];
    const f16x8 dx = *(const f16x8*)&tileA[p * 8];
    const f16x8 mk8 = {mk, mk, mk, mk, mk, mk, mk, mk};
    const f16x8 xo = dx * mk8 + xB;           // v_pk_fma_f16 x4
    *(f16x8*)(dst + (size_t)gp * 8) = xo;
  }
}

// ---- projection: out[p] = bp + sum_c x[p][c]*Wp[c] ----
__global__ void proj_kernel(const _Float16* __restrict__ x,
                            const float* __restrict__ Wp,
                            const float* __restrict__ bp,
                            float* __restrict__ out) {
  int p = blockIdx.x * blockDim.x + threadIdx.x;
  if (p >= HH * WW) return;
  const f16x8 xv = *(const f16x8*)(x + (size_t)p * 8);
  float acc = bp[0];
#pragma unroll
  for (int c = 0; c < SD; ++c) acc = fmaf((float)xv[c], Wp[c], acc);
  out[p] = acc;
}

extern "C" void kernel_launch(void* const* d_in, const int* in_sizes, int n_in,
                              void* d_out, int out_size, void* d_ws, size_t ws_size,
                              hipStream_t stream) {
  (void)in_sizes; (void)n_in; (void)out_size; (void)ws_size;
  const float* seed = (const float*)d_in[0];
  const float* W1   = (const float*)d_in[1];
  const float* b1   = (const float*)d_in[2];
  const float* W2   = (const float*)d_in[3];
  const float* b2   = (const float*)d_in[4];
  const float* Wp   = (const float*)d_in[5];
  const float* bp   = (const float*)d_in[6];
  float* out  = (float*)d_out;
  _Float16* buf0 = (_Float16*)d_ws;
  _Float16* buf1 = buf0 + (size_t)SD * HH * WW;
  _Float16* w1f  = buf1 + (size_t)SD * HH * WW;
  _Float16* w2f  = w1f + 2 * 3 * 64 * 8;

  // 64 subkeys of jax.random.split(jax.random.key(42), 64) (raw pairs, no xor)
  uint32_t ka[64], kb[64];
  for (int i = 0; i < 64; ++i) tf2x32(0u, 42u, 0u, (uint32_t)i, ka[i], kb[i]);

  hipLaunchKernelGGL(prep_kernel, dim3(1), dim3(256), 0, stream, W1, W2, w1f, w2f);
  hipLaunchKernelGGL(init_kernel, dim3((HH * WW) / 256), dim3(256), 0, stream, seed, buf0);

  dim3 grid(WW / TX, HH / TY);   // 32x32 = 1024 blocks = 4/CU exact
  _Float16* s = buf0; _Float16* d = buf1;
  for (int i = 0; i < 64; i += 2) {
    hipLaunchKernelGGL(step2_kernel, grid, dim3(512), 0, stream,
                       s, d, w1f, w2f, b1, b2, ka[i], kb[i], ka[i + 1], kb[i + 1]);
    _Float16* t = s; s = d; d = t;
  }
  hipLaunchKernelGGL(proj_kernel, dim3((HH * WW) / 256), dim3(256), 0, stream,
                     s, Wp, bp, out);
}